// Round 5
// baseline (1154.441 us; speedup 1.0000x reference)
//
#include <hip/hip_runtime.h>
#include <cstddef>

// Problem constants
#define BB 32
#define NN 128
#define PP 8128

typedef __attribute__((ext_vector_type(8))) short short8;
typedef __attribute__((ext_vector_type(4))) float floatx4;

union U4S8 { uint4 u; short8 s; };
__device__ __forceinline__ short8 as_s8(uint4 v){ U4S8 x; x.u = v; return x.s; }

// ---------- bf16 helpers ----------
__device__ __forceinline__ float bf_lo(unsigned u){ union{unsigned v;float f;}x; x.v=u<<16; return x.f; }
__device__ __forceinline__ float bf_hi(unsigned u){ union{unsigned v;float f;}x; x.v=u&0xffff0000u; return x.f; }
__device__ __forceinline__ unsigned pack_bf16(float a, float b){
  union{float f;unsigned u;}xa,xb; xa.f=a; xb.f=b;
  unsigned ua=xa.u, ub=xb.u;
  ua = (ua + 0x7fffu + ((ua>>16)&1u)) >> 16;
  ub = (ub + 0x7fffu + ((ub>>16)&1u)) >> 16;
  return (ua & 0xffffu) | (ub << 16);
}
__device__ __forceinline__ unsigned short bf16_1(float a){
  union{float f;unsigned u;}x; x.f=a;
  return (unsigned short)((x.u + 0x7fffu + ((x.u>>16)&1u)) >> 16);
}
__device__ __forceinline__ float sigf(float x){ return 1.f/(1.f + __expf(-x)); }

// ---------- weight conversion + emb table: f32 [K][C] -> bf16 k-pair layout [C][K/2] ----------
__global__ __launch_bounds__(256,4) void conv_w_kernel(
  const float* __restrict__ Wl_e, const float* __restrict__ Wm_e,
  const float* __restrict__ Wu_e, const float* __restrict__ Wu_m,
  const float* __restrict__ Wr1, const float* __restrict__ emb,
  unsigned* __restrict__ wT, unsigned* __restrict__ wr1T, unsigned* __restrict__ embT)
{
  int tid = blockIdx.x*256 + threadIdx.x;   // 65536 total
  if (tid < 256) {
    int id = tid >> 6, k2 = tid & 63;
    embT[tid] = pack_bf16(emb[id*128 + 2*k2], emb[id*128 + 2*k2 + 1]);
  }
  if (tid < 32768) {
    int mat = tid >> 13, r = tid & 8191;
    int k2 = r >> 7, c = r & 127;
    const float* W = (mat==0) ? Wl_e : (mat==1) ? Wm_e : (mat==2) ? Wu_e : Wu_m;
    wT[mat*8192 + c*64 + k2] = pack_bf16(W[(2*k2)*128 + c], W[(2*k2+1)*128 + c]);
  } else {
    int r = tid - 32768;
    int k2 = r >> 8, c = r & 255;
    wr1T[(size_t)c*128 + k2] = pack_bf16(Wr1[(2*k2)*256 + c], Wr1[(2*k2+1)*256 + c]);
  }
}

// ---------- fused GRU + node projections ----------
// grid = B*32 (4 rows/block), block 256 = 4 row-lanes x 64. do_gru=0: project h_in only.
__global__ __launch_bounds__(256,4) void gru_proj_kernel(
  int do_gru,
  const float* __restrict__ ms, const float* __restrict__ h_in, float* __restrict__ h_out,
  const float* __restrict__ W_ih, const float* __restrict__ W_hh,
  const float* __restrict__ b_ih, const float* __restrict__ b_hh,
  const float* __restrict__ Wl_w, const float* __restrict__ Wl_v,
  const float* __restrict__ Wm_w, const float* __restrict__ Wm_v,
  const int* __restrict__ event_nums,
  float* __restrict__ a_l, float* __restrict__ b_l,
  float* __restrict__ a_m, float* __restrict__ b_m)
{
  __shared__ float h_s[4][128];
  __shared__ float ms_s[4][128];
  const int t = threadIdx.x, blk = blockIdx.x;
  const int b = blk >> 5, n0 = (blk & 31) * 4;
  const int vn = event_nums[b];
  const int g = t >> 6, l = t & 63;
  const int row = b*128 + n0 + g;

  h_s[g][l]    = h_in[(size_t)row*128 + l];
  h_s[g][l+64] = h_in[(size_t)row*128 + l + 64];
  if (do_gru) {
    ms_s[g][l]    = ms[(size_t)row*128 + l];
    ms_s[g][l+64] = ms[(size_t)row*128 + l + 64];
  }
  __syncthreads();

  if (do_gru) {
    float acc[12] = {};
    #pragma unroll 4
    for (int k = 0; k < 128; ++k) {
      float mv = ms_s[g][k], hv = h_s[g][k];
      #pragma unroll
      for (int u = 0; u < 6; ++u) {
        acc[u]   += mv * W_ih[(size_t)k*384 + l + 64*u];
        acc[6+u] += hv * W_hh[(size_t)k*384 + l + 64*u];
      }
    }
    const bool valid = (n0 + g) < vn;
    float hnew[2];
    #pragma unroll
    for (int u = 0; u < 2; ++u) {
      int c = l + 64*u;
      float ir = acc[u]     + b_ih[c];
      float iz = acc[u+2]   + b_ih[128+c];
      float in_= acc[u+4]   + b_ih[256+c];
      float hr = acc[6+u]   + b_hh[c];
      float hz = acc[8+u]   + b_hh[128+c];
      float hn = acc[10+u]  + b_hh[256+c];
      float r  = sigf(ir + hr);
      float zg = sigf(iz + hz);
      float nn = tanhf(in_ + r*hn);
      float hold = h_s[g][c];
      hnew[u] = valid ? (1.f - zg)*nn + zg*hold : hold;
    }
    __syncthreads();
    #pragma unroll
    for (int u = 0; u < 2; ++u) {
      int c = l + 64*u;
      h_s[g][c] = hnew[u];
      h_out[(size_t)row*128 + c] = hnew[u];
    }
    __syncthreads();
  }

  // projections from (possibly updated) h_s
  {
    const float* Wp[4] = {Wl_w, Wl_v, Wm_w, Wm_v};
    float* Op[4] = {a_l, b_l, a_m, b_m};
    float acc2[8] = {};
    #pragma unroll 4
    for (int k = 0; k < 128; ++k) {
      float hv = h_s[g][k];
      #pragma unroll
      for (int u = 0; u < 8; ++u)
        acc2[u] += hv * Wp[u>>1][(size_t)k*128 + l + 64*(u&1)];
    }
    #pragma unroll
    for (int u = 0; u < 8; ++u)
      Op[u>>1][(size_t)row*128 + l + 64*(u&1)] = acc2[u];
  }
}

// ---------- fused MFMA edge-round kernel ----------
// grid = B*N (one workgroup per (b,j)), block 256 = 4 waves in 2x2 (rowhalf x colhalf).
// Single K-pass computes Z, M0, U_e simultaneously. A-loads fully hoisted for MLP.
__global__ __launch_bounds__(256,2) void edge_round_mfma(
  unsigned* __restrict__ eg,           // [B][N(j)][N(i)][64] bf16-pairs
  const unsigned* __restrict__ wT,     // [Wl_e|Wm_e|Wu_e|Wu_m] each [c][64] bf16-pairs
  const unsigned* __restrict__ embT,   // [4][64] bf16-pairs
  const int* __restrict__ ids,         // [B][N][N]
  int first,
  const float* __restrict__ a_l, const float* __restrict__ b_l,
  const float* __restrict__ a_m, const float* __restrict__ b_m,
  const float* __restrict__ bl1, const float* __restrict__ wl2,
  const float* __restrict__ bl2, const float* __restrict__ bm,
  const float* __restrict__ bu,
  const int* __restrict__ event_nums,
  float* __restrict__ ms)
{
  __shared__ unsigned m_a[128*68];   // m (later u) as bf16, padded rows (68 words = 136 halves)
  __shared__ float adj[128], svec[128], msum[128];
  __shared__ float bL_s[128], bM_s[128], bu_s[128], wl2_s[128];
  __shared__ unsigned emb_s[4*68];
  __shared__ int id_s[128];
  unsigned short* m16 = (unsigned short*)m_a;

  const int t = threadIdx.x;
  const int b = blockIdx.x >> 7, j = blockIdx.x & 127;
  const int vn = event_nums[b];
  unsigned* eblk = eg + (size_t)(b*128 + j) * 8192;   // 128 rows x 64 k2

  if (j >= vn) {
    if (t < 128) ms[(size_t)(b*128 + j)*128 + t] = 0.f;
    return;
  }

  if (t < 128) {
    bL_s[t] = b_l[(size_t)(b*128 + j)*128 + t] + bl1[t];
    bM_s[t] = b_m[(size_t)(b*128 + j)*128 + t] + bm[t];
    bu_s[t] = bu[t];
    wl2_s[t] = wl2[t];
    adj[t] = 0.f; msum[t] = 0.f;
    if (first) id_s[t] = ids[((size_t)(b*128 + t))*128 + j];
  }
  if (first && t < 256) emb_s[(t >> 6)*68 + (t & 63)] = embT[t];
  __syncthreads();

  const int lane = t & 63, wv = t >> 6;
  const int q = lane >> 4, n = lane & 15;
  const int rh = wv >> 1, ch = wv & 1;

  const unsigned* wz  = wT;
  const unsigned* wm  = wT + 8192;
  const unsigned* wue = wT + 16384;
  const unsigned* wum = wT + 24576;

  int colg[4];
  #pragma unroll
  for (int ct = 0; ct < 4; ++ct) colg[ct] = ch*64 + ct*16 + n;

  int arowi[4];
  #pragma unroll
  for (int rt = 0; rt < 4; ++rt) arowi[rt] = rh*64 + rt*16 + n;

  // ---------- hoisted A-loads: 16 independent dwordx4 in flight per thread ----------
  uint4 areg[4][4];   // [kb][rt]
  if (first) {
    int aid[4];
    #pragma unroll
    for (int rt = 0; rt < 4; ++rt) aid[rt] = id_s[arowi[rt]];
    #pragma unroll
    for (int kb = 0; kb < 4; ++kb)
      #pragma unroll
      for (int rt = 0; rt < 4; ++rt)
        areg[kb][rt] = *(const uint4*)&emb_s[aid[rt]*68 + kb*16 + q*4];
  } else {
    #pragma unroll
    for (int kb = 0; kb < 4; ++kb)
      #pragma unroll
      for (int rt = 0; rt < 4; ++rt)
        areg[kb][rt] = *(const uint4*)(eblk + arowi[rt]*64 + kb*16 + q*4);
  }

  // ---------- fused K-pass: Z = E@Wl_e, M0 = E@Wm_e, U = E@Wu_e ----------
  floatx4 accz[4][4], accm[4][4], accu[4][4];
  #pragma unroll
  for (int rt = 0; rt < 4; ++rt)
    #pragma unroll
    for (int ct = 0; ct < 4; ++ct) {
      accz[rt][ct] = (floatx4){0.f,0.f,0.f,0.f};
      accm[rt][ct] = (floatx4){0.f,0.f,0.f,0.f};
      accu[rt][ct] = (floatx4){0.f,0.f,0.f,0.f};
    }
  #pragma unroll
  for (int kb = 0; kb < 4; ++kb) {
    uint4 bb[4];
    #pragma unroll
    for (int ct = 0; ct < 4; ++ct) bb[ct] = *(const uint4*)(wz + colg[ct]*64 + kb*16 + q*4);
    #pragma unroll
    for (int rt = 0; rt < 4; ++rt)
      #pragma unroll
      for (int ct = 0; ct < 4; ++ct)
        accz[rt][ct] = __builtin_amdgcn_mfma_f32_16x16x32_bf16(as_s8(areg[kb][rt]), as_s8(bb[ct]), accz[rt][ct], 0, 0, 0);
    #pragma unroll
    for (int ct = 0; ct < 4; ++ct) bb[ct] = *(const uint4*)(wm + colg[ct]*64 + kb*16 + q*4);
    #pragma unroll
    for (int rt = 0; rt < 4; ++rt)
      #pragma unroll
      for (int ct = 0; ct < 4; ++ct)
        accm[rt][ct] = __builtin_amdgcn_mfma_f32_16x16x32_bf16(as_s8(areg[kb][rt]), as_s8(bb[ct]), accm[rt][ct], 0, 0, 0);
    #pragma unroll
    for (int ct = 0; ct < 4; ++ct) bb[ct] = *(const uint4*)(wue + colg[ct]*64 + kb*16 + q*4);
    #pragma unroll
    for (int rt = 0; rt < 4; ++rt)
      #pragma unroll
      for (int ct = 0; ct < 4; ++ct)
        accu[rt][ct] = __builtin_amdgcn_mfma_f32_16x16x32_bf16(as_s8(areg[kb][rt]), as_s8(bb[ct]), accu[rt][ct], 0, 0, 0);
  }

  // z epilogue: adj[row] += sum_col relu(z + a_l + bL) * wl2
  {
    float wl2v[4], bLv[4];
    #pragma unroll
    for (int ct = 0; ct < 4; ++ct) { wl2v[ct] = wl2_s[colg[ct]]; bLv[ct] = bL_s[colg[ct]]; }
    #pragma unroll
    for (int rt = 0; rt < 4; ++rt) {
      float szr[4] = {0.f,0.f,0.f,0.f};
      #pragma unroll
      for (int ct = 0; ct < 4; ++ct) {
        #pragma unroll
        for (int r = 0; r < 4; ++r) {
          int row = rh*64 + rt*16 + q*4 + r;
          float al = a_l[(size_t)(b*128 + row)*128 + colg[ct]];
          float zv = fmaxf(accz[rt][ct][r] + al + bLv[ct], 0.f);
          szr[r] += zv * wl2v[ct];
        }
      }
      #pragma unroll
      for (int r = 0; r < 4; ++r) {
        szr[r] += __shfl_xor(szr[r], 1);
        szr[r] += __shfl_xor(szr[r], 2);
        szr[r] += __shfl_xor(szr[r], 4);
        szr[r] += __shfl_xor(szr[r], 8);
      }
      if (n == 0) {
        #pragma unroll
        for (int r = 0; r < 4; ++r)
          atomicAdd(&adj[rh*64 + rt*16 + q*4 + r], szr[r]);
      }
    }
  }
  __syncthreads();
  if (t < 128) svec[t] = sigf(adj[t] + bl2[0]);
  __syncthreads();

  // m epilogue: m = relu(m0 + a_m + bM) * svec[row] (masked) -> m_a bf16; column sums -> msum
  {
    float bMv[4];
    #pragma unroll
    for (int ct = 0; ct < 4; ++ct) bMv[ct] = bM_s[colg[ct]];
    float colsum[4] = {0.f,0.f,0.f,0.f};
    #pragma unroll
    for (int rt = 0; rt < 4; ++rt) {
      #pragma unroll
      for (int ct = 0; ct < 4; ++ct) {
        #pragma unroll
        for (int r = 0; r < 4; ++r) {
          int row = rh*64 + rt*16 + q*4 + r;
          float am = a_m[(size_t)(b*128 + row)*128 + colg[ct]];
          float mv = fmaxf(accm[rt][ct][r] + am + bMv[ct], 0.f);
          float sc = (row < vn) ? svec[row] : 0.f;
          mv *= sc;
          m16[row*136 + colg[ct]] = bf16_1(mv);
          colsum[ct] += mv;
        }
      }
    }
    #pragma unroll
    for (int ct = 0; ct < 4; ++ct) {
      float v = colsum[ct];
      v += __shfl_xor(v, 16);
      v += __shfl_xor(v, 32);
      if (lane < 16) atomicAdd(&msum[colg[ct]], v);
    }
  }
  __syncthreads();
  if (t < 128) ms[(size_t)(b*128 + j)*128 + t] = msum[t];

  // ---------- GEMM: U += M @ Wu_m (M resident in LDS) ----------
  #pragma unroll
  for (int kb = 0; kb < 4; ++kb) {
    uint4 a[4], bb[4];
    #pragma unroll
    for (int rt = 0; rt < 4; ++rt) a[rt] = *(const uint4*)&m_a[arowi[rt]*68 + kb*16 + q*4];
    #pragma unroll
    for (int ct = 0; ct < 4; ++ct) bb[ct] = *(const uint4*)(wum + colg[ct]*64 + kb*16 + q*4);
    #pragma unroll
    for (int rt = 0; rt < 4; ++rt)
      #pragma unroll
      for (int ct = 0; ct < 4; ++ct)
        accu[rt][ct] = __builtin_amdgcn_mfma_f32_16x16x32_bf16(as_s8(a[rt]), as_s8(bb[ct]), accu[rt][ct], 0, 0, 0);
  }
  __syncthreads();   // all m_a reads done before overwrite

  // u epilogue -> m_a (bf16), then coalesced copy-out of valid rows
  {
    float buv[4];
    #pragma unroll
    for (int ct = 0; ct < 4; ++ct) buv[ct] = bu_s[colg[ct]];
    #pragma unroll
    for (int rt = 0; rt < 4; ++rt)
      #pragma unroll
      for (int ct = 0; ct < 4; ++ct)
        #pragma unroll
        for (int r = 0; r < 4; ++r) {
          int row = rh*64 + rt*16 + q*4 + r;
          m16[row*136 + colg[ct]] = bf16_1(fmaxf(accu[rt][ct][r] + buv[ct], 0.f));
        }
  }
  __syncthreads();
  #pragma unroll
  for (int it = 0; it < 32; ++it) {
    int f = it*256 + t;
    int row = f >> 6, c2 = f & 63;
    if (row < vn) eblk[row*64 + c2] = m_a[row*68 + c2];
  }
}

// ---------- MFMA readout ----------
// grid = B*254 (32 pairs/block), block 256 = 4 waves over 4 column-quarters of 256.
// h16 overlays f_s (disjoint lifetimes) to cut LDS -> 3 blocks/CU.
__global__ __launch_bounds__(256,3) void readout_mfma(
  const unsigned* __restrict__ eg,
  const unsigned* __restrict__ wr1T,   // [256 cols][128 k2] bf16-pairs
  const float* __restrict__ br1,
  const float* __restrict__ Wr2, const float* __restrict__ br2,
  const int* __restrict__ event_nums, float* __restrict__ out)
{
  __shared__ unsigned f_s[32*132];            // feat bf16 pairs, padded rows; later reused as h16
  __shared__ float w2_s[2560];
  __shared__ int iu_s[32], ju_s[32];
  unsigned short* h16 = (unsigned short*)f_s; // overlay: 32 rows x 264 halves = 32x132 words

  const int t = threadIdx.x;
  const int b = blockIdx.x / 254, pb = blockIdx.x % 254;
  const int vn = event_nums[b];

  if (t < 32) {
    int p = pb*32 + t;
    float disc = (float)((2*NN-1)*(2*NN-1) - 8*p);
    int iu = (int)(((float)(2*NN-1) - sqrtf(disc)) * 0.5f);
    if (iu < 0) iu = 0; if (iu > NN-2) iu = NN-2;
    while (iu < NN-2 && ((iu+1)*(2*NN-2-iu))/2 <= p) ++iu;
    while (iu > 0 && (iu*(2*NN-1-iu))/2 > p) --iu;
    int ju = p - (iu*(2*NN-1-iu))/2 + iu + 1;
    iu_s[t] = iu; ju_s[t] = ju;
  }
  #pragma unroll
  for (int rep = 0; rep < 10; ++rep) {
    int idx = rep*256 + t;
    if (idx < 2560) w2_s[idx] = Wr2[idx];
  }
  __syncthreads();

  // stage feat: row pr = pair, word w: [0,64)=e[b,iu,ju,:], [64,128)=e[b,ju,iu,:]
  #pragma unroll
  for (int it = 0; it < 16; ++it) {
    int f = it*256 + t;
    int pr = f >> 7, w = f & 127;
    int side = w >> 6, k2l = w & 63;
    int iu = iu_s[pr], ju = ju_s[pr];
    size_t base = side ? (((size_t)(b*128 + iu))*128 + ju)*64
                       : (((size_t)(b*128 + ju))*128 + iu)*64;
    f_s[pr*132 + w] = eg[base + k2l];
  }
  __syncthreads();

  const int lane = t & 63, wv = t >> 6;
  const int q = lane >> 4, n = lane & 15;
  int colg[4];
  #pragma unroll
  for (int ct = 0; ct < 4; ++ct) colg[ct] = wv*64 + ct*16 + n;

  floatx4 acc[2][4];
  #pragma unroll
  for (int rt = 0; rt < 2; ++rt)
    #pragma unroll
    for (int ct = 0; ct < 4; ++ct) acc[rt][ct] = (floatx4){0.f,0.f,0.f,0.f};

  #pragma unroll
  for (int kb = 0; kb < 8; ++kb) {
    uint4 a[2], bb[4];
    #pragma unroll
    for (int rt = 0; rt < 2; ++rt) a[rt] = *(const uint4*)&f_s[(rt*16 + n)*132 + kb*16 + q*4];
    #pragma unroll
    for (int ct = 0; ct < 4; ++ct) bb[ct] = *(const uint4*)(wr1T + (size_t)colg[ct]*128 + kb*16 + q*4);
    #pragma unroll
    for (int rt = 0; rt < 2; ++rt)
      #pragma unroll
      for (int ct = 0; ct < 4; ++ct)
        acc[rt][ct] = __builtin_amdgcn_mfma_f32_16x16x32_bf16(as_s8(a[rt]), as_s8(bb[ct]), acc[rt][ct], 0, 0, 0);
  }
  __syncthreads();   // all f_s reads complete before h16 overlay writes

  {
    float brv[4];
    #pragma unroll
    for (int ct = 0; ct < 4; ++ct) brv[ct] = br1[colg[ct]];
    #pragma unroll
    for (int rt = 0; rt < 2; ++rt)
      #pragma unroll
      for (int ct = 0; ct < 4; ++ct)
        #pragma unroll
        for (int r = 0; r < 4; ++r) {
          int pr = rt*16 + q*4 + r;
          h16[pr*264 + colg[ct]] = bf16_1(fmaxf(acc[rt][ct][r] + brv[ct], 0.f));
        }
  }
  __syncthreads();

  const unsigned* h32 = (const unsigned*)h16;
  #pragma unroll
  for (int rep = 0; rep < 2; ++rep) {
    int oi = rep*256 + t;
    if (oi < 320) {
      int row = oi / 10, o = oi - row*10;
      float a = br2[o];
      #pragma unroll 4
      for (int c2 = 0; c2 < 128; ++c2) {
        unsigned u = h32[row*132 + c2];
        a += bf_lo(u)*w2_s[(2*c2)*10 + o] + bf_hi(u)*w2_s[(2*c2+1)*10 + o];
      }
      int iu = iu_s[row], ju = ju_s[row];
      if (ju < vn) {
        int idx = iu*vn - (iu*(iu+1))/2 + (ju - iu - 1);
        out[(((size_t)b*5 + (o>>1))*PP + idx)*2 + (o&1)] = a;
      }
    }
  }
}

extern "C" void kernel_launch(void* const* d_in, const int* in_sizes, int n_in,
                              void* d_out, int out_size, void* d_ws, size_t ws_size,
                              hipStream_t stream) {
  const int*   edge_ids      = (const int*)d_in[0];
  const float* node_features = (const float*)d_in[1];
  const int*   event_nums    = (const int*)d_in[3];
  const float* emb  = (const float*)d_in[4];
  const float* Wl_e = (const float*)d_in[5];
  const float* Wl_w = (const float*)d_in[6];
  const float* Wl_v = (const float*)d_in[7];
  const float* bl1  = (const float*)d_in[8];
  const float* wl2  = (const float*)d_in[9];
  const float* bl2  = (const float*)d_in[10];
  const float* Wm_w = (const float*)d_in[11];
  const float* Wm_v = (const float*)d_in[12];
  const float* Wm_e = (const float*)d_in[13];
  const float* bm   = (const float*)d_in[14];
  const float* Wu_e = (const float*)d_in[15];
  const float* Wu_m = (const float*)d_in[16];
  const float* bu   = (const float*)d_in[17];
  const float* W_ih = (const float*)d_in[18];
  const float* W_hh = (const float*)d_in[19];
  const float* b_ih = (const float*)d_in[20];
  const float* b_hh = (const float*)d_in[21];
  const float* Wr1  = (const float*)d_in[22];
  const float* br1  = (const float*)d_in[23];
  const float* Wr2  = (const float*)d_in[24];
  const float* br2  = (const float*)d_in[25];

  // workspace carve: e_g 134.2 MB + 6 small (12.6 MB) + packed weights (0.26 MB) + embT
  const size_t SZ_E = (size_t)134217728;       // B*N*N*64 u32
  const size_t SZ_S = (size_t)2097152;         // B*N*128 f32
  const size_t SZ_W = (size_t)131072;          // 32768 u32
  const size_t SZ_EM = (size_t)4096;
  const size_t need = SZ_E + 6*SZ_S + 2*SZ_W + SZ_EM;

  hipMemsetAsync(d_out, 0, (size_t)out_size * sizeof(float), stream);
  if (ws_size < need) return;   // clean failure instead of OOB fault

  char* w = (char*)d_ws;
  unsigned* eg   = (unsigned*)w; w += SZ_E;
  float* h_ws = (float*)w; w += SZ_S;
  float* a_l  = (float*)w; w += SZ_S;
  float* b_l  = (float*)w; w += SZ_S;
  float* a_m  = (float*)w; w += SZ_S;
  float* b_m  = (float*)w; w += SZ_S;
  float* ms   = (float*)w; w += SZ_S;
  unsigned* wT   = (unsigned*)w; w += SZ_W;
  unsigned* wr1T = (unsigned*)w; w += SZ_W;
  unsigned* embT = (unsigned*)w; w += SZ_EM;

  hipLaunchKernelGGL(conv_w_kernel, dim3(256), dim3(256), 0, stream,
      Wl_e, Wm_e, Wu_e, Wu_m, Wr1, emb, wT, wr1T, embT);

  hipLaunchKernelGGL(gru_proj_kernel, dim3(1024), dim3(256), 0, stream,
      0, ms, node_features, h_ws, W_ih, W_hh, b_ih, b_hh,
      Wl_w, Wl_v, Wm_w, Wm_v, event_nums, a_l, b_l, a_m, b_m);

  for (int r = 0; r < 3; ++r) {
    hipLaunchKernelGGL(edge_round_mfma, dim3(4096), dim3(256), 0, stream,
        eg, wT, embT, edge_ids, (r == 0) ? 1 : 0, a_l, b_l, a_m, b_m,
        bl1, wl2, bl2, bm, bu, event_nums, ms);
    if (r < 2) {
      const float* hin = (r == 0) ? node_features : h_ws;
      hipLaunchKernelGGL(gru_proj_kernel, dim3(1024), dim3(256), 0, stream,
          1, ms, hin, h_ws, W_ih, W_hh, b_ih, b_hh,
          Wl_w, Wl_v, Wm_w, Wm_v, event_nums, a_l, b_l, a_m, b_m);
    }
  }

  hipLaunchKernelGGL(readout_mfma, dim3(8128), dim3(256), 0, stream,
      eg, wr1T, br1, Wr2, br2, event_nums, (float*)d_out);
}

// Round 6
// 973.667 us; speedup vs baseline: 1.1857x; 1.1857x over previous
//
#include <hip/hip_runtime.h>
#include <cstddef>

// Problem constants
#define BB 32
#define NN 128
#define PP 8128

typedef __attribute__((ext_vector_type(8))) short short8;
typedef __attribute__((ext_vector_type(4))) float floatx4;

union U4S8 { uint4 u; short8 s; };
__device__ __forceinline__ short8 as_s8(uint4 v){ U4S8 x; x.u = v; return x.s; }

// ---------- bf16 helpers ----------
__device__ __forceinline__ float bf_lo(unsigned u){ union{unsigned v;float f;}x; x.v=u<<16; return x.f; }
__device__ __forceinline__ float bf_hi(unsigned u){ union{unsigned v;float f;}x; x.v=u&0xffff0000u; return x.f; }
__device__ __forceinline__ unsigned pack_bf16(float a, float b){
  union{float f;unsigned u;}xa,xb; xa.f=a; xb.f=b;
  unsigned ua=xa.u, ub=xb.u;
  ua = (ua + 0x7fffu + ((ua>>16)&1u)) >> 16;
  ub = (ub + 0x7fffu + ((ub>>16)&1u)) >> 16;
  return (ua & 0xffffu) | (ub << 16);
}
__device__ __forceinline__ unsigned short bf16_1(float a){
  union{float f;unsigned u;}x; x.f=a;
  return (unsigned short)((x.u + 0x7fffu + ((x.u>>16)&1u)) >> 16);
}
__device__ __forceinline__ float sigf(float x){ return 1.f/(1.f + __expf(-x)); }

// ---------- weight conversion + emb table: f32 [K][C] -> bf16 k-pair layout [C][K/2] ----------
__global__ __launch_bounds__(256,4) void conv_w_kernel(
  const float* __restrict__ Wl_e, const float* __restrict__ Wm_e,
  const float* __restrict__ Wu_e, const float* __restrict__ Wu_m,
  const float* __restrict__ Wr1, const float* __restrict__ emb,
  unsigned* __restrict__ wT, unsigned* __restrict__ wr1T, unsigned* __restrict__ embT)
{
  int tid = blockIdx.x*256 + threadIdx.x;   // 65536 total
  if (tid < 256) {
    int id = tid >> 6, k2 = tid & 63;
    embT[tid] = pack_bf16(emb[id*128 + 2*k2], emb[id*128 + 2*k2 + 1]);
  }
  if (tid < 32768) {
    int mat = tid >> 13, r = tid & 8191;
    int k2 = r >> 7, c = r & 127;
    const float* W = (mat==0) ? Wl_e : (mat==1) ? Wm_e : (mat==2) ? Wu_e : Wu_m;
    wT[mat*8192 + c*64 + k2] = pack_bf16(W[(2*k2)*128 + c], W[(2*k2+1)*128 + c]);
  } else {
    int r = tid - 32768;
    int k2 = r >> 8, c = r & 255;
    wr1T[(size_t)c*128 + k2] = pack_bf16(Wr1[(2*k2)*256 + c], Wr1[(2*k2+1)*256 + c]);
  }
}

// ---------- fused GRU + node projections ----------
// grid = B*32 (4 rows/block), block 256 = 4 row-lanes x 64. do_gru=0: project h_in only.
__global__ __launch_bounds__(256,4) void gru_proj_kernel(
  int do_gru,
  const float* __restrict__ ms, const float* __restrict__ h_in, float* __restrict__ h_out,
  const float* __restrict__ W_ih, const float* __restrict__ W_hh,
  const float* __restrict__ b_ih, const float* __restrict__ b_hh,
  const float* __restrict__ Wl_w, const float* __restrict__ Wl_v,
  const float* __restrict__ Wm_w, const float* __restrict__ Wm_v,
  const int* __restrict__ event_nums,
  float* __restrict__ a_l, float* __restrict__ b_l,
  float* __restrict__ a_m, float* __restrict__ b_m)
{
  __shared__ float h_s[4][128];
  __shared__ float ms_s[4][128];
  const int t = threadIdx.x, blk = blockIdx.x;
  const int b = blk >> 5, n0 = (blk & 31) * 4;
  const int vn = event_nums[b];
  const int g = t >> 6, l = t & 63;
  const int row = b*128 + n0 + g;

  h_s[g][l]    = h_in[(size_t)row*128 + l];
  h_s[g][l+64] = h_in[(size_t)row*128 + l + 64];
  if (do_gru) {
    ms_s[g][l]    = ms[(size_t)row*128 + l];
    ms_s[g][l+64] = ms[(size_t)row*128 + l + 64];
  }
  __syncthreads();

  if (do_gru) {
    float acc[12] = {};
    #pragma unroll 4
    for (int k = 0; k < 128; ++k) {
      float mv = ms_s[g][k], hv = h_s[g][k];
      #pragma unroll
      for (int u = 0; u < 6; ++u) {
        acc[u]   += mv * W_ih[(size_t)k*384 + l + 64*u];
        acc[6+u] += hv * W_hh[(size_t)k*384 + l + 64*u];
      }
    }
    const bool valid = (n0 + g) < vn;
    float hnew[2];
    #pragma unroll
    for (int u = 0; u < 2; ++u) {
      int c = l + 64*u;
      float ir = acc[u]     + b_ih[c];
      float iz = acc[u+2]   + b_ih[128+c];
      float in_= acc[u+4]   + b_ih[256+c];
      float hr = acc[6+u]   + b_hh[c];
      float hz = acc[8+u]   + b_hh[128+c];
      float hn = acc[10+u]  + b_hh[256+c];
      float r  = sigf(ir + hr);
      float zg = sigf(iz + hz);
      float nn = tanhf(in_ + r*hn);
      float hold = h_s[g][c];
      hnew[u] = valid ? (1.f - zg)*nn + zg*hold : hold;
    }
    __syncthreads();
    #pragma unroll
    for (int u = 0; u < 2; ++u) {
      int c = l + 64*u;
      h_s[g][c] = hnew[u];
      h_out[(size_t)row*128 + c] = hnew[u];
    }
    __syncthreads();
  }

  // projections from (possibly updated) h_s
  {
    const float* Wp[4] = {Wl_w, Wl_v, Wm_w, Wm_v};
    float* Op[4] = {a_l, b_l, a_m, b_m};
    float acc2[8] = {};
    #pragma unroll 4
    for (int k = 0; k < 128; ++k) {
      float hv = h_s[g][k];
      #pragma unroll
      for (int u = 0; u < 8; ++u)
        acc2[u] += hv * Wp[u>>1][(size_t)k*128 + l + 64*(u&1)];
    }
    #pragma unroll
    for (int u = 0; u < 8; ++u)
      Op[u>>1][(size_t)row*128 + l + 64*(u&1)] = acc2[u];
  }
}

// ---------- fused MFMA edge-round kernel ----------
// grid = B*N (one workgroup per (b,j)), block 256 = 4 waves in 2x2 (rowhalf x colhalf).
// A-loads hoisted once (areg stays live all kernel). K-passes split to fit the
// 256-reg unified file at 2 waves/SIMD: pass1 = Z+M (areg+128 acc ~= 230 live),
// pass2 = U (areg+64 acc ~= 170 live). No spills expected.
__global__ __launch_bounds__(256,2) void edge_round_mfma(
  unsigned* __restrict__ eg,           // [B][N(j)][N(i)][64] bf16-pairs
  const unsigned* __restrict__ wT,     // [Wl_e|Wm_e|Wu_e|Wu_m] each [c][64] bf16-pairs
  const unsigned* __restrict__ embT,   // [4][64] bf16-pairs
  const int* __restrict__ ids,         // [B][N][N]
  int first,
  const float* __restrict__ a_l, const float* __restrict__ b_l,
  const float* __restrict__ a_m, const float* __restrict__ b_m,
  const float* __restrict__ bl1, const float* __restrict__ wl2,
  const float* __restrict__ bl2, const float* __restrict__ bm,
  const float* __restrict__ bu,
  const int* __restrict__ event_nums,
  float* __restrict__ ms)
{
  __shared__ unsigned m_a[128*68];   // m (later u) as bf16, padded rows (68 words = 136 halves)
  __shared__ float adj[128], svec[128], msum[128];
  __shared__ float bL_s[128], bM_s[128], bu_s[128], wl2_s[128];
  __shared__ unsigned emb_s[4*68];
  __shared__ int id_s[128];
  unsigned short* m16 = (unsigned short*)m_a;

  const int t = threadIdx.x;
  const int b = blockIdx.x >> 7, j = blockIdx.x & 127;
  const int vn = event_nums[b];
  unsigned* eblk = eg + (size_t)(b*128 + j) * 8192;   // 128 rows x 64 k2

  if (j >= vn) {
    if (t < 128) ms[(size_t)(b*128 + j)*128 + t] = 0.f;
    return;
  }

  if (t < 128) {
    bL_s[t] = b_l[(size_t)(b*128 + j)*128 + t] + bl1[t];
    bM_s[t] = b_m[(size_t)(b*128 + j)*128 + t] + bm[t];
    bu_s[t] = bu[t];
    wl2_s[t] = wl2[t];
    adj[t] = 0.f; msum[t] = 0.f;
    if (first) id_s[t] = ids[((size_t)(b*128 + t))*128 + j];
  }
  if (first && t < 256) emb_s[(t >> 6)*68 + (t & 63)] = embT[t];
  __syncthreads();

  const int lane = t & 63, wv = t >> 6;
  const int q = lane >> 4, n = lane & 15;
  const int rh = wv >> 1, ch = wv & 1;

  const unsigned* wz  = wT;
  const unsigned* wm  = wT + 8192;
  const unsigned* wue = wT + 16384;
  const unsigned* wum = wT + 24576;

  int colg[4];
  #pragma unroll
  for (int ct = 0; ct < 4; ++ct) colg[ct] = ch*64 + ct*16 + n;

  int arowi[4];
  #pragma unroll
  for (int rt = 0; rt < 4; ++rt) arowi[rt] = rh*64 + rt*16 + n;

  // ---------- hoisted A-loads: 16 independent dwordx4, live for the whole kernel ----------
  uint4 areg[4][4];   // [kb][rt]
  if (first) {
    int aid[4];
    #pragma unroll
    for (int rt = 0; rt < 4; ++rt) aid[rt] = id_s[arowi[rt]];
    #pragma unroll
    for (int kb = 0; kb < 4; ++kb)
      #pragma unroll
      for (int rt = 0; rt < 4; ++rt)
        areg[kb][rt] = *(const uint4*)&emb_s[aid[rt]*68 + kb*16 + q*4];
  } else {
    #pragma unroll
    for (int kb = 0; kb < 4; ++kb)
      #pragma unroll
      for (int rt = 0; rt < 4; ++rt)
        areg[kb][rt] = *(const uint4*)(eblk + arowi[rt]*64 + kb*16 + q*4);
  }

  // ---------- PASS 1: Z = E@Wl_e, M0 = E@Wm_e (two accumulators live) ----------
  {
    floatx4 accz[4][4], accm[4][4];
    #pragma unroll
    for (int rt = 0; rt < 4; ++rt)
      #pragma unroll
      for (int ct = 0; ct < 4; ++ct) {
        accz[rt][ct] = (floatx4){0.f,0.f,0.f,0.f};
        accm[rt][ct] = (floatx4){0.f,0.f,0.f,0.f};
      }
    #pragma unroll
    for (int kb = 0; kb < 4; ++kb) {
      uint4 bb[4];
      #pragma unroll
      for (int ct = 0; ct < 4; ++ct) bb[ct] = *(const uint4*)(wz + colg[ct]*64 + kb*16 + q*4);
      #pragma unroll
      for (int rt = 0; rt < 4; ++rt)
        #pragma unroll
        for (int ct = 0; ct < 4; ++ct)
          accz[rt][ct] = __builtin_amdgcn_mfma_f32_16x16x32_bf16(as_s8(areg[kb][rt]), as_s8(bb[ct]), accz[rt][ct], 0, 0, 0);
      #pragma unroll
      for (int ct = 0; ct < 4; ++ct) bb[ct] = *(const uint4*)(wm + colg[ct]*64 + kb*16 + q*4);
      #pragma unroll
      for (int rt = 0; rt < 4; ++rt)
        #pragma unroll
        for (int ct = 0; ct < 4; ++ct)
          accm[rt][ct] = __builtin_amdgcn_mfma_f32_16x16x32_bf16(as_s8(areg[kb][rt]), as_s8(bb[ct]), accm[rt][ct], 0, 0, 0);
    }

    // z epilogue: adj[row] += sum_col relu(z + a_l + bL) * wl2
    {
      float wl2v[4], bLv[4];
      #pragma unroll
      for (int ct = 0; ct < 4; ++ct) { wl2v[ct] = wl2_s[colg[ct]]; bLv[ct] = bL_s[colg[ct]]; }
      #pragma unroll
      for (int rt = 0; rt < 4; ++rt) {
        float szr[4] = {0.f,0.f,0.f,0.f};
        #pragma unroll
        for (int ct = 0; ct < 4; ++ct) {
          #pragma unroll
          for (int r = 0; r < 4; ++r) {
            int row = rh*64 + rt*16 + q*4 + r;
            float al = a_l[(size_t)(b*128 + row)*128 + colg[ct]];
            float zv = fmaxf(accz[rt][ct][r] + al + bLv[ct], 0.f);
            szr[r] += zv * wl2v[ct];
          }
        }
        #pragma unroll
        for (int r = 0; r < 4; ++r) {
          szr[r] += __shfl_xor(szr[r], 1);
          szr[r] += __shfl_xor(szr[r], 2);
          szr[r] += __shfl_xor(szr[r], 4);
          szr[r] += __shfl_xor(szr[r], 8);
        }
        if (n == 0) {
          #pragma unroll
          for (int r = 0; r < 4; ++r)
            atomicAdd(&adj[rh*64 + rt*16 + q*4 + r], szr[r]);
        }
      }
    }
    __syncthreads();
    if (t < 128) svec[t] = sigf(adj[t] + bl2[0]);
    __syncthreads();

    // m epilogue: m = relu(m0 + a_m + bM) * svec[row] (masked) -> m_a bf16; column sums -> msum
    {
      float bMv[4];
      #pragma unroll
      for (int ct = 0; ct < 4; ++ct) bMv[ct] = bM_s[colg[ct]];
      float colsum[4] = {0.f,0.f,0.f,0.f};
      #pragma unroll
      for (int rt = 0; rt < 4; ++rt) {
        #pragma unroll
        for (int ct = 0; ct < 4; ++ct) {
          #pragma unroll
          for (int r = 0; r < 4; ++r) {
            int row = rh*64 + rt*16 + q*4 + r;
            float am = a_m[(size_t)(b*128 + row)*128 + colg[ct]];
            float mv = fmaxf(accm[rt][ct][r] + am + bMv[ct], 0.f);
            float sc = (row < vn) ? svec[row] : 0.f;
            mv *= sc;
            m16[row*136 + colg[ct]] = bf16_1(mv);
            colsum[ct] += mv;
          }
        }
      }
      #pragma unroll
      for (int ct = 0; ct < 4; ++ct) {
        float v = colsum[ct];
        v += __shfl_xor(v, 16);
        v += __shfl_xor(v, 32);
        if (lane < 16) atomicAdd(&msum[colg[ct]], v);
      }
    }
  }
  __syncthreads();
  if (t < 128) ms[(size_t)(b*128 + j)*128 + t] = msum[t];

  // ---------- PASS 2: U = E@Wu_e + M@Wu_m (single accumulator live) ----------
  floatx4 accu[4][4];
  #pragma unroll
  for (int rt = 0; rt < 4; ++rt)
    #pragma unroll
    for (int ct = 0; ct < 4; ++ct) accu[rt][ct] = (floatx4){0.f,0.f,0.f,0.f};
  #pragma unroll
  for (int kb = 0; kb < 4; ++kb) {
    uint4 bb[4];
    #pragma unroll
    for (int ct = 0; ct < 4; ++ct) bb[ct] = *(const uint4*)(wue + colg[ct]*64 + kb*16 + q*4);
    #pragma unroll
    for (int rt = 0; rt < 4; ++rt)
      #pragma unroll
      for (int ct = 0; ct < 4; ++ct)
        accu[rt][ct] = __builtin_amdgcn_mfma_f32_16x16x32_bf16(as_s8(areg[kb][rt]), as_s8(bb[ct]), accu[rt][ct], 0, 0, 0);
  }
  #pragma unroll
  for (int kb = 0; kb < 4; ++kb) {
    uint4 a[4], bb[4];
    #pragma unroll
    for (int rt = 0; rt < 4; ++rt) a[rt] = *(const uint4*)&m_a[arowi[rt]*68 + kb*16 + q*4];
    #pragma unroll
    for (int ct = 0; ct < 4; ++ct) bb[ct] = *(const uint4*)(wum + colg[ct]*64 + kb*16 + q*4);
    #pragma unroll
    for (int rt = 0; rt < 4; ++rt)
      #pragma unroll
      for (int ct = 0; ct < 4; ++ct)
        accu[rt][ct] = __builtin_amdgcn_mfma_f32_16x16x32_bf16(as_s8(a[rt]), as_s8(bb[ct]), accu[rt][ct], 0, 0, 0);
  }
  __syncthreads();   // all m_a reads done before overwrite

  // u epilogue -> m_a (bf16), then coalesced copy-out of valid rows
  {
    float buv[4];
    #pragma unroll
    for (int ct = 0; ct < 4; ++ct) buv[ct] = bu_s[colg[ct]];
    #pragma unroll
    for (int rt = 0; rt < 4; ++rt)
      #pragma unroll
      for (int ct = 0; ct < 4; ++ct)
        #pragma unroll
        for (int r = 0; r < 4; ++r) {
          int row = rh*64 + rt*16 + q*4 + r;
          m16[row*136 + colg[ct]] = bf16_1(fmaxf(accu[rt][ct][r] + buv[ct], 0.f));
        }
  }
  __syncthreads();
  #pragma unroll
  for (int it = 0; it < 32; ++it) {
    int f = it*256 + t;
    int row = f >> 6, c2 = f & 63;
    if (row < vn) eblk[row*64 + c2] = m_a[row*68 + c2];
  }
}

// ---------- MFMA readout ----------
// grid = B*254 (32 pairs/block), block 256 = 4 waves over 4 column-quarters of 256.
// h16 overlays f_s (disjoint lifetimes) to cut LDS -> 3 blocks/CU.
__global__ __launch_bounds__(256,3) void readout_mfma(
  const unsigned* __restrict__ eg,
  const unsigned* __restrict__ wr1T,   // [256 cols][128 k2] bf16-pairs
  const float* __restrict__ br1,
  const float* __restrict__ Wr2, const float* __restrict__ br2,
  const int* __restrict__ event_nums, float* __restrict__ out)
{
  __shared__ unsigned f_s[32*132];            // feat bf16 pairs, padded rows; later reused as h16
  __shared__ float w2_s[2560];
  __shared__ int iu_s[32], ju_s[32];
  unsigned short* h16 = (unsigned short*)f_s; // overlay: 32 rows x 264 halves = 32x132 words

  const int t = threadIdx.x;
  const int b = blockIdx.x / 254, pb = blockIdx.x % 254;
  const int vn = event_nums[b];

  if (t < 32) {
    int p = pb*32 + t;
    float disc = (float)((2*NN-1)*(2*NN-1) - 8*p);
    int iu = (int)(((float)(2*NN-1) - sqrtf(disc)) * 0.5f);
    if (iu < 0) iu = 0; if (iu > NN-2) iu = NN-2;
    while (iu < NN-2 && ((iu+1)*(2*NN-2-iu))/2 <= p) ++iu;
    while (iu > 0 && (iu*(2*NN-1-iu))/2 > p) --iu;
    int ju = p - (iu*(2*NN-1-iu))/2 + iu + 1;
    iu_s[t] = iu; ju_s[t] = ju;
  }
  #pragma unroll
  for (int rep = 0; rep < 10; ++rep) {
    int idx = rep*256 + t;
    if (idx < 2560) w2_s[idx] = Wr2[idx];
  }
  __syncthreads();

  // stage feat: row pr = pair, word w: [0,64)=e[b,iu,ju,:], [64,128)=e[b,ju,iu,:]
  #pragma unroll
  for (int it = 0; it < 16; ++it) {
    int f = it*256 + t;
    int pr = f >> 7, w = f & 127;
    int side = w >> 6, k2l = w & 63;
    int iu = iu_s[pr], ju = ju_s[pr];
    size_t base = side ? (((size_t)(b*128 + iu))*128 + ju)*64
                       : (((size_t)(b*128 + ju))*128 + iu)*64;
    f_s[pr*132 + w] = eg[base + k2l];
  }
  __syncthreads();

  const int lane = t & 63, wv = t >> 6;
  const int q = lane >> 4, n = lane & 15;
  int colg[4];
  #pragma unroll
  for (int ct = 0; ct < 4; ++ct) colg[ct] = wv*64 + ct*16 + n;

  floatx4 acc[2][4];
  #pragma unroll
  for (int rt = 0; rt < 2; ++rt)
    #pragma unroll
    for (int ct = 0; ct < 4; ++ct) acc[rt][ct] = (floatx4){0.f,0.f,0.f,0.f};

  #pragma unroll
  for (int kb = 0; kb < 8; ++kb) {
    uint4 a[2], bb[4];
    #pragma unroll
    for (int rt = 0; rt < 2; ++rt) a[rt] = *(const uint4*)&f_s[(rt*16 + n)*132 + kb*16 + q*4];
    #pragma unroll
    for (int ct = 0; ct < 4; ++ct) bb[ct] = *(const uint4*)(wr1T + (size_t)colg[ct]*128 + kb*16 + q*4);
    #pragma unroll
    for (int rt = 0; rt < 2; ++rt)
      #pragma unroll
      for (int ct = 0; ct < 4; ++ct)
        acc[rt][ct] = __builtin_amdgcn_mfma_f32_16x16x32_bf16(as_s8(a[rt]), as_s8(bb[ct]), acc[rt][ct], 0, 0, 0);
  }
  __syncthreads();   // all f_s reads complete before h16 overlay writes

  {
    float brv[4];
    #pragma unroll
    for (int ct = 0; ct < 4; ++ct) brv[ct] = br1[colg[ct]];
    #pragma unroll
    for (int rt = 0; rt < 2; ++rt)
      #pragma unroll
      for (int ct = 0; ct < 4; ++ct)
        #pragma unroll
        for (int r = 0; r < 4; ++r) {
          int pr = rt*16 + q*4 + r;
          h16[pr*264 + colg[ct]] = bf16_1(fmaxf(acc[rt][ct][r] + brv[ct], 0.f));
        }
  }
  __syncthreads();

  const unsigned* h32 = (const unsigned*)h16;
  #pragma unroll
  for (int rep = 0; rep < 2; ++rep) {
    int oi = rep*256 + t;
    if (oi < 320) {
      int row = oi / 10, o = oi - row*10;
      float a = br2[o];
      #pragma unroll 4
      for (int c2 = 0; c2 < 128; ++c2) {
        unsigned u = h32[row*132 + c2];
        a += bf_lo(u)*w2_s[(2*c2)*10 + o] + bf_hi(u)*w2_s[(2*c2+1)*10 + o];
      }
      int iu = iu_s[row], ju = ju_s[row];
      if (ju < vn) {
        int idx = iu*vn - (iu*(iu+1))/2 + (ju - iu - 1);
        out[(((size_t)b*5 + (o>>1))*PP + idx)*2 + (o&1)] = a;
      }
    }
  }
}

extern "C" void kernel_launch(void* const* d_in, const int* in_sizes, int n_in,
                              void* d_out, int out_size, void* d_ws, size_t ws_size,
                              hipStream_t stream) {
  const int*   edge_ids      = (const int*)d_in[0];
  const float* node_features = (const float*)d_in[1];
  const int*   event_nums    = (const int*)d_in[3];
  const float* emb  = (const float*)d_in[4];
  const float* Wl_e = (const float*)d_in[5];
  const float* Wl_w = (const float*)d_in[6];
  const float* Wl_v = (const float*)d_in[7];
  const float* bl1  = (const float*)d_in[8];
  const float* wl2  = (const float*)d_in[9];
  const float* bl2  = (const float*)d_in[10];
  const float* Wm_w = (const float*)d_in[11];
  const float* Wm_v = (const float*)d_in[12];
  const float* Wm_e = (const float*)d_in[13];
  const float* bm   = (const float*)d_in[14];
  const float* Wu_e = (const float*)d_in[15];
  const float* Wu_m = (const float*)d_in[16];
  const float* bu   = (const float*)d_in[17];
  const float* W_ih = (const float*)d_in[18];
  const float* W_hh = (const float*)d_in[19];
  const float* b_ih = (const float*)d_in[20];
  const float* b_hh = (const float*)d_in[21];
  const float* Wr1  = (const float*)d_in[22];
  const float* br1  = (const float*)d_in[23];
  const float* Wr2  = (const float*)d_in[24];
  const float* br2  = (const float*)d_in[25];

  // workspace carve: e_g 134.2 MB + 6 small (12.6 MB) + packed weights (0.26 MB) + embT
  const size_t SZ_E = (size_t)134217728;       // B*N*N*64 u32
  const size_t SZ_S = (size_t)2097152;         // B*N*128 f32
  const size_t SZ_W = (size_t)131072;          // 32768 u32
  const size_t SZ_EM = (size_t)4096;
  const size_t need = SZ_E + 6*SZ_S + 2*SZ_W + SZ_EM;

  hipMemsetAsync(d_out, 0, (size_t)out_size * sizeof(float), stream);
  if (ws_size < need) return;   // clean failure instead of OOB fault

  char* w = (char*)d_ws;
  unsigned* eg   = (unsigned*)w; w += SZ_E;
  float* h_ws = (float*)w; w += SZ_S;
  float* a_l  = (float*)w; w += SZ_S;
  float* b_l  = (float*)w; w += SZ_S;
  float* a_m  = (float*)w; w += SZ_S;
  float* b_m  = (float*)w; w += SZ_S;
  float* ms   = (float*)w; w += SZ_S;
  unsigned* wT   = (unsigned*)w; w += SZ_W;
  unsigned* wr1T = (unsigned*)w; w += SZ_W;
  unsigned* embT = (unsigned*)w; w += SZ_EM;

  hipLaunchKernelGGL(conv_w_kernel, dim3(256), dim3(256), 0, stream,
      Wl_e, Wm_e, Wu_e, Wu_m, Wr1, emb, wT, wr1T, embT);

  hipLaunchKernelGGL(gru_proj_kernel, dim3(1024), dim3(256), 0, stream,
      0, ms, node_features, h_ws, W_ih, W_hh, b_ih, b_hh,
      Wl_w, Wl_v, Wm_w, Wm_v, event_nums, a_l, b_l, a_m, b_m);

  for (int r = 0; r < 3; ++r) {
    hipLaunchKernelGGL(edge_round_mfma, dim3(4096), dim3(256), 0, stream,
        eg, wT, embT, edge_ids, (r == 0) ? 1 : 0, a_l, b_l, a_m, b_m,
        bl1, wl2, bl2, bm, bu, event_nums, ms);
    if (r < 2) {
      const float* hin = (r == 0) ? node_features : h_ws;
      hipLaunchKernelGGL(gru_proj_kernel, dim3(1024), dim3(256), 0, stream,
          1, ms, hin, h_ws, W_ih, W_hh, b_ih, b_hh,
          Wl_w, Wl_v, Wm_w, Wm_v, event_nums, a_l, b_l, a_m, b_m);
    }
  }

  hipLaunchKernelGGL(readout_mfma, dim3(8128), dim3(256), 0, stream,
      eg, wr1T, br1, Wr2, br2, event_nums, (float*)d_out);
}

// Round 7
// 853.220 us; speedup vs baseline: 1.3530x; 1.1412x over previous
//
#include <hip/hip_runtime.h>
#include <cstddef>

// Problem constants
#define BB 32
#define NN 128
#define PP 8128

typedef __attribute__((ext_vector_type(8))) short short8;
typedef __attribute__((ext_vector_type(4))) float floatx4;

union U4S8 { uint4 u; short8 s; };
__device__ __forceinline__ short8 as_s8(uint4 v){ U4S8 x; x.u = v; return x.s; }

// ---------- bf16 helpers ----------
__device__ __forceinline__ float bf_lo(unsigned u){ union{unsigned v;float f;}x; x.v=u<<16; return x.f; }
__device__ __forceinline__ float bf_hi(unsigned u){ union{unsigned v;float f;}x; x.v=u&0xffff0000u; return x.f; }
__device__ __forceinline__ unsigned pack_bf16(float a, float b){
  union{float f;unsigned u;}xa,xb; xa.f=a; xb.f=b;
  unsigned ua=xa.u, ub=xb.u;
  ua = (ua + 0x7fffu + ((ua>>16)&1u)) >> 16;
  ub = (ub + 0x7fffu + ((ub>>16)&1u)) >> 16;
  return (ua & 0xffffu) | (ub << 16);
}
__device__ __forceinline__ unsigned short bf16_1(float a){
  union{float f;unsigned u;}x; x.f=a;
  return (unsigned short)((x.u + 0x7fffu + ((x.u>>16)&1u)) >> 16);
}
__device__ __forceinline__ float sigf(float x){ return 1.f/(1.f + __expf(-x)); }

// ---------- weight conversion + emb table: f32 [K][C] -> bf16 k-pair layout [C][K/2] ----------
__global__ __launch_bounds__(256,4) void conv_w_kernel(
  const float* __restrict__ Wl_e, const float* __restrict__ Wm_e,
  const float* __restrict__ Wu_e, const float* __restrict__ Wu_m,
  const float* __restrict__ Wr1, const float* __restrict__ emb,
  unsigned* __restrict__ wT, unsigned* __restrict__ wr1T, unsigned* __restrict__ embT)
{
  int tid = blockIdx.x*256 + threadIdx.x;   // 65536 total
  if (tid < 256) {
    int id = tid >> 6, k2 = tid & 63;
    embT[tid] = pack_bf16(emb[id*128 + 2*k2], emb[id*128 + 2*k2 + 1]);
  }
  if (tid < 32768) {
    int mat = tid >> 13, r = tid & 8191;
    int k2 = r >> 7, c = r & 127;
    const float* W = (mat==0) ? Wl_e : (mat==1) ? Wm_e : (mat==2) ? Wu_e : Wu_m;
    wT[mat*8192 + c*64 + k2] = pack_bf16(W[(2*k2)*128 + c], W[(2*k2+1)*128 + c]);
  } else {
    int r = tid - 32768;
    int k2 = r >> 8, c = r & 255;
    wr1T[(size_t)c*128 + k2] = pack_bf16(Wr1[(2*k2)*256 + c], Wr1[(2*k2+1)*256 + c]);
  }
}

// ---------- fused GRU + node projections ----------
// grid = B*32 (4 rows/block), block 256 = 4 row-lanes x 64. do_gru=0: project h_in only.
__global__ __launch_bounds__(256,4) void gru_proj_kernel(
  int do_gru,
  const float* __restrict__ ms, const float* __restrict__ h_in, float* __restrict__ h_out,
  const float* __restrict__ W_ih, const float* __restrict__ W_hh,
  const float* __restrict__ b_ih, const float* __restrict__ b_hh,
  const float* __restrict__ Wl_w, const float* __restrict__ Wl_v,
  const float* __restrict__ Wm_w, const float* __restrict__ Wm_v,
  const int* __restrict__ event_nums,
  float* __restrict__ a_l, float* __restrict__ b_l,
  float* __restrict__ a_m, float* __restrict__ b_m)
{
  __shared__ float h_s[4][128];
  __shared__ float ms_s[4][128];
  const int t = threadIdx.x, blk = blockIdx.x;
  const int b = blk >> 5, n0 = (blk & 31) * 4;
  const int vn = event_nums[b];
  const int g = t >> 6, l = t & 63;
  const int row = b*128 + n0 + g;

  h_s[g][l]    = h_in[(size_t)row*128 + l];
  h_s[g][l+64] = h_in[(size_t)row*128 + l + 64];
  if (do_gru) {
    ms_s[g][l]    = ms[(size_t)row*128 + l];
    ms_s[g][l+64] = ms[(size_t)row*128 + l + 64];
  }
  __syncthreads();

  if (do_gru) {
    float acc[12] = {};
    #pragma unroll 4
    for (int k = 0; k < 128; ++k) {
      float mv = ms_s[g][k], hv = h_s[g][k];
      #pragma unroll
      for (int u = 0; u < 6; ++u) {
        acc[u]   += mv * W_ih[(size_t)k*384 + l + 64*u];
        acc[6+u] += hv * W_hh[(size_t)k*384 + l + 64*u];
      }
    }
    const bool valid = (n0 + g) < vn;
    float hnew[2];
    #pragma unroll
    for (int u = 0; u < 2; ++u) {
      int c = l + 64*u;
      float ir = acc[u]     + b_ih[c];
      float iz = acc[u+2]   + b_ih[128+c];
      float in_= acc[u+4]   + b_ih[256+c];
      float hr = acc[6+u]   + b_hh[c];
      float hz = acc[8+u]   + b_hh[128+c];
      float hn = acc[10+u]  + b_hh[256+c];
      float r  = sigf(ir + hr);
      float zg = sigf(iz + hz);
      float nn = tanhf(in_ + r*hn);
      float hold = h_s[g][c];
      hnew[u] = valid ? (1.f - zg)*nn + zg*hold : hold;
    }
    __syncthreads();
    #pragma unroll
    for (int u = 0; u < 2; ++u) {
      int c = l + 64*u;
      h_s[g][c] = hnew[u];
      h_out[(size_t)row*128 + c] = hnew[u];
    }
    __syncthreads();
  }

  // projections from (possibly updated) h_s
  {
    const float* Wp[4] = {Wl_w, Wl_v, Wm_w, Wm_v};
    float* Op[4] = {a_l, b_l, a_m, b_m};
    float acc2[8] = {};
    #pragma unroll 4
    for (int k = 0; k < 128; ++k) {
      float hv = h_s[g][k];
      #pragma unroll
      for (int u = 0; u < 8; ++u)
        acc2[u] += hv * Wp[u>>1][(size_t)k*128 + l + 64*(u&1)];
    }
    #pragma unroll
    for (int u = 0; u < 8; ++u)
      Op[u>>1][(size_t)row*128 + l + 64*(u&1)] = acc2[u];
  }
}

// ---------- fused MFMA edge-round kernel ----------
// grid = B*N (one workgroup per (b,j)), block 256 = 4 waves in 2x2 (rowhalf x colhalf).
// E staged in LDS (no register hoist -> no spill); acc lives in AGPR.
// Row-tiles fully above vn are skipped (wave-uniform guard).
__global__ __launch_bounds__(256,2) void edge_round_mfma(
  unsigned* __restrict__ eg,           // [B][N(j)][N(i)][64] bf16-pairs
  const unsigned* __restrict__ wT,     // [Wl_e|Wm_e|Wu_e|Wu_m] each [c][64] bf16-pairs
  const unsigned* __restrict__ embT,   // [4][64] bf16-pairs
  const int* __restrict__ ids,         // [B][N][N]
  int first,
  const float* __restrict__ a_l, const float* __restrict__ b_l,
  const float* __restrict__ a_m, const float* __restrict__ b_m,
  const float* __restrict__ bl1, const float* __restrict__ wl2,
  const float* __restrict__ bl2, const float* __restrict__ bm,
  const float* __restrict__ bu,
  const int* __restrict__ event_nums,
  float* __restrict__ ms)
{
  __shared__ unsigned e_s[128*68];   // E as bf16 k-pairs, padded rows (68 words)
  __shared__ unsigned m_a[128*68];   // m (later u) as bf16, padded rows
  __shared__ float adj[128], svec[128], msum[128];
  __shared__ float bL_s[128], bM_s[128], bu_s[128], wl2_s[128];
  __shared__ unsigned emb_s[4*68];
  __shared__ int id_s[128];
  unsigned short* m16 = (unsigned short*)m_a;

  const int t = threadIdx.x;
  const int b = blockIdx.x >> 7, j = blockIdx.x & 127;
  const int vn = event_nums[b];
  unsigned* eblk = eg + (size_t)(b*128 + j) * 8192;   // 128 rows x 64 k2

  if (j >= vn) {
    if (t < 128) ms[(size_t)(b*128 + j)*128 + t] = 0.f;
    return;
  }

  if (t < 128) {
    bL_s[t] = b_l[(size_t)(b*128 + j)*128 + t] + bl1[t];
    bM_s[t] = b_m[(size_t)(b*128 + j)*128 + t] + bm[t];
    bu_s[t] = bu[t];
    wl2_s[t] = wl2[t];
    adj[t] = 0.f; msum[t] = 0.f;
    if (first) id_s[t] = ids[((size_t)(b*128 + t))*128 + j];
  }
  if (first && t < 256) emb_s[(t >> 6)*68 + (t & 63)] = embT[t];
  __syncthreads();

  const int vnc16 = (vn + 15) & ~15;   // rows to stage (tile granularity)

  // ---------- stage E into LDS (coalesced dwordx4; only valid tiles) ----------
  {
    const int srow = t >> 4, c4 = (t & 15) * 4;
    #pragma unroll
    for (int it = 0; it < 8; ++it) {
      int row = it*16 + srow;
      if (row < vnc16) {
        uint4 v;
        if (first) v = *(const uint4*)&emb_s[id_s[row]*68 + c4];
        else       v = *(const uint4*)&eblk[row*64 + c4];
        *(uint4*)&e_s[row*68 + c4] = v;
      }
    }
  }
  __syncthreads();

  const int lane = t & 63, wv = t >> 6;
  const int q = lane >> 4, n = lane & 15;
  const int rh = wv >> 1, ch = wv & 1;

  // number of valid 16-row tiles for this wave's row-half (wave-uniform)
  int nvt = (vn - rh*64 + 15) >> 4;
  nvt = nvt < 0 ? 0 : (nvt > 4 ? 4 : nvt);

  const unsigned* wz  = wT;
  const unsigned* wm  = wT + 8192;
  const unsigned* wue = wT + 16384;
  const unsigned* wum = wT + 24576;

  int colg[4];
  #pragma unroll
  for (int ct = 0; ct < 4; ++ct) colg[ct] = ch*64 + ct*16 + n;

  int arowi[4];
  #pragma unroll
  for (int rt = 0; rt < 4; ++rt) arowi[rt] = rh*64 + rt*16 + n;

  // ---------- PASS 1: Z = E@Wl_e, M0 = E@Wm_e ----------
  {
    floatx4 accz[4][4], accm[4][4];
    #pragma unroll
    for (int rt = 0; rt < 4; ++rt)
      #pragma unroll
      for (int ct = 0; ct < 4; ++ct) {
        accz[rt][ct] = (floatx4){0.f,0.f,0.f,0.f};
        accm[rt][ct] = (floatx4){0.f,0.f,0.f,0.f};
      }
    #pragma unroll
    for (int kb = 0; kb < 4; ++kb) {
      uint4 bz[4], bm4[4];
      #pragma unroll
      for (int ct = 0; ct < 4; ++ct) {
        bz[ct]  = *(const uint4*)(wz + colg[ct]*64 + kb*16 + q*4);
        bm4[ct] = *(const uint4*)(wm + colg[ct]*64 + kb*16 + q*4);
      }
      #pragma unroll
      for (int rt = 0; rt < 4; ++rt) {
        if (rt < nvt) {
          uint4 a = *(const uint4*)&e_s[arowi[rt]*68 + kb*16 + q*4];
          #pragma unroll
          for (int ct = 0; ct < 4; ++ct)
            accz[rt][ct] = __builtin_amdgcn_mfma_f32_16x16x32_bf16(as_s8(a), as_s8(bz[ct]), accz[rt][ct], 0, 0, 0);
          #pragma unroll
          for (int ct = 0; ct < 4; ++ct)
            accm[rt][ct] = __builtin_amdgcn_mfma_f32_16x16x32_bf16(as_s8(a), as_s8(bm4[ct]), accm[rt][ct], 0, 0, 0);
        }
      }
    }

    // z epilogue: adj[row] += sum_col relu(z + a_l + bL) * wl2
    {
      float wl2v[4], bLv[4];
      #pragma unroll
      for (int ct = 0; ct < 4; ++ct) { wl2v[ct] = wl2_s[colg[ct]]; bLv[ct] = bL_s[colg[ct]]; }
      #pragma unroll
      for (int rt = 0; rt < 4; ++rt) {
        if (rt < nvt) {
          float szr[4] = {0.f,0.f,0.f,0.f};
          #pragma unroll
          for (int ct = 0; ct < 4; ++ct) {
            #pragma unroll
            for (int r = 0; r < 4; ++r) {
              int row = rh*64 + rt*16 + q*4 + r;
              float al = a_l[(size_t)(b*128 + row)*128 + colg[ct]];
              float zv = fmaxf(accz[rt][ct][r] + al + bLv[ct], 0.f);
              szr[r] += zv * wl2v[ct];
            }
          }
          #pragma unroll
          for (int r = 0; r < 4; ++r) {
            szr[r] += __shfl_xor(szr[r], 1);
            szr[r] += __shfl_xor(szr[r], 2);
            szr[r] += __shfl_xor(szr[r], 4);
            szr[r] += __shfl_xor(szr[r], 8);
          }
          if (n == 0) {
            #pragma unroll
            for (int r = 0; r < 4; ++r)
              atomicAdd(&adj[rh*64 + rt*16 + q*4 + r], szr[r]);
          }
        }
      }
    }
    __syncthreads();
    if (t < 128) svec[t] = sigf(adj[t] + bl2[0]);
    __syncthreads();

    // m epilogue: m = relu(m0 + a_m + bM) * svec[row] (masked) -> m_a bf16; column sums -> msum
    {
      float bMv[4];
      #pragma unroll
      for (int ct = 0; ct < 4; ++ct) bMv[ct] = bM_s[colg[ct]];
      float colsum[4] = {0.f,0.f,0.f,0.f};
      #pragma unroll
      for (int rt = 0; rt < 4; ++rt) {
        if (rt < nvt) {
          #pragma unroll
          for (int ct = 0; ct < 4; ++ct) {
            #pragma unroll
            for (int r = 0; r < 4; ++r) {
              int row = rh*64 + rt*16 + q*4 + r;
              float am = a_m[(size_t)(b*128 + row)*128 + colg[ct]];
              float mv = fmaxf(accm[rt][ct][r] + am + bMv[ct], 0.f);
              float sc = (row < vn) ? svec[row] : 0.f;
              mv *= sc;
              m16[row*136 + colg[ct]] = bf16_1(mv);
              colsum[ct] += mv;
            }
          }
        }
      }
      #pragma unroll
      for (int ct = 0; ct < 4; ++ct) {
        float v = colsum[ct];
        v += __shfl_xor(v, 16);
        v += __shfl_xor(v, 32);
        if (lane < 16) atomicAdd(&msum[colg[ct]], v);
      }
    }
  }
  __syncthreads();
  if (t < 128) ms[(size_t)(b*128 + j)*128 + t] = msum[t];

  // ---------- PASS 2: U = E@Wu_e + M@Wu_m ----------
  floatx4 accu[4][4];
  #pragma unroll
  for (int rt = 0; rt < 4; ++rt)
    #pragma unroll
    for (int ct = 0; ct < 4; ++ct) accu[rt][ct] = (floatx4){0.f,0.f,0.f,0.f};
  #pragma unroll
  for (int kb = 0; kb < 4; ++kb) {
    uint4 bb[4];
    #pragma unroll
    for (int ct = 0; ct < 4; ++ct) bb[ct] = *(const uint4*)(wue + colg[ct]*64 + kb*16 + q*4);
    #pragma unroll
    for (int rt = 0; rt < 4; ++rt) {
      if (rt < nvt) {
        uint4 a = *(const uint4*)&e_s[arowi[rt]*68 + kb*16 + q*4];
        #pragma unroll
        for (int ct = 0; ct < 4; ++ct)
          accu[rt][ct] = __builtin_amdgcn_mfma_f32_16x16x32_bf16(as_s8(a), as_s8(bb[ct]), accu[rt][ct], 0, 0, 0);
      }
    }
  }
  #pragma unroll
  for (int kb = 0; kb < 4; ++kb) {
    uint4 bb[4];
    #pragma unroll
    for (int ct = 0; ct < 4; ++ct) bb[ct] = *(const uint4*)(wum + colg[ct]*64 + kb*16 + q*4);
    #pragma unroll
    for (int rt = 0; rt < 4; ++rt) {
      if (rt < nvt) {
        uint4 a = *(const uint4*)&m_a[arowi[rt]*68 + kb*16 + q*4];
        #pragma unroll
        for (int ct = 0; ct < 4; ++ct)
          accu[rt][ct] = __builtin_amdgcn_mfma_f32_16x16x32_bf16(as_s8(a), as_s8(bb[ct]), accu[rt][ct], 0, 0, 0);
      }
    }
  }
  __syncthreads();   // all m_a reads done before overwrite

  // u epilogue -> m_a (bf16), then coalesced copy-out of valid rows
  {
    float buv[4];
    #pragma unroll
    for (int ct = 0; ct < 4; ++ct) buv[ct] = bu_s[colg[ct]];
    #pragma unroll
    for (int rt = 0; rt < 4; ++rt) {
      if (rt < nvt) {
        #pragma unroll
        for (int ct = 0; ct < 4; ++ct)
          #pragma unroll
          for (int r = 0; r < 4; ++r) {
            int row = rh*64 + rt*16 + q*4 + r;
            m16[row*136 + colg[ct]] = bf16_1(fmaxf(accu[rt][ct][r] + buv[ct], 0.f));
          }
      }
    }
  }
  __syncthreads();
  #pragma unroll
  for (int it = 0; it < 32; ++it) {
    int f = it*256 + t;
    int row = f >> 6, c2 = f & 63;
    if (row < vn) eblk[row*64 + c2] = m_a[row*68 + c2];
  }
}

// ---------- MFMA readout ----------
// grid = B*254 (32 pairs/block), block 256 = 4 waves over 4 column-quarters of 256.
// h16 overlays f_s (disjoint lifetimes) to cut LDS -> 3 blocks/CU.
__global__ __launch_bounds__(256,3) void readout_mfma(
  const unsigned* __restrict__ eg,
  const unsigned* __restrict__ wr1T,   // [256 cols][128 k2] bf16-pairs
  const float* __restrict__ br1,
  const float* __restrict__ Wr2, const float* __restrict__ br2,
  const int* __restrict__ event_nums, float* __restrict__ out)
{
  __shared__ unsigned f_s[32*132];            // feat bf16 pairs, padded rows; later reused as h16
  __shared__ float w2_s[2560];
  __shared__ int iu_s[32], ju_s[32];
  unsigned short* h16 = (unsigned short*)f_s; // overlay: 32 rows x 264 halves = 32x132 words

  const int t = threadIdx.x;
  const int b = blockIdx.x / 254, pb = blockIdx.x % 254;
  const int vn = event_nums[b];

  if (t < 32) {
    int p = pb*32 + t;
    float disc = (float)((2*NN-1)*(2*NN-1) - 8*p);
    int iu = (int)(((float)(2*NN-1) - sqrtf(disc)) * 0.5f);
    if (iu < 0) iu = 0; if (iu > NN-2) iu = NN-2;
    while (iu < NN-2 && ((iu+1)*(2*NN-2-iu))/2 <= p) ++iu;
    while (iu > 0 && (iu*(2*NN-1-iu))/2 > p) --iu;
    int ju = p - (iu*(2*NN-1-iu))/2 + iu + 1;
    iu_s[t] = iu; ju_s[t] = ju;
  }
  #pragma unroll
  for (int rep = 0; rep < 10; ++rep) {
    int idx = rep*256 + t;
    if (idx < 2560) w2_s[idx] = Wr2[idx];
  }
  __syncthreads();

  // stage feat: row pr = pair, word w: [0,64)=e[b,iu,ju,:], [64,128)=e[b,ju,iu,:]
  #pragma unroll
  for (int it = 0; it < 16; ++it) {
    int f = it*256 + t;
    int pr = f >> 7, w = f & 127;
    int side = w >> 6, k2l = w & 63;
    int iu = iu_s[pr], ju = ju_s[pr];
    size_t base = side ? (((size_t)(b*128 + iu))*128 + ju)*64
                       : (((size_t)(b*128 + ju))*128 + iu)*64;
    f_s[pr*132 + w] = eg[base + k2l];
  }
  __syncthreads();

  const int lane = t & 63, wv = t >> 6;
  const int q = lane >> 4, n = lane & 15;
  int colg[4];
  #pragma unroll
  for (int ct = 0; ct < 4; ++ct) colg[ct] = wv*64 + ct*16 + n;

  floatx4 acc[2][4];
  #pragma unroll
  for (int rt = 0; rt < 2; ++rt)
    #pragma unroll
    for (int ct = 0; ct < 4; ++ct) acc[rt][ct] = (floatx4){0.f,0.f,0.f,0.f};

  #pragma unroll
  for (int kb = 0; kb < 8; ++kb) {
    uint4 a[2], bb[4];
    #pragma unroll
    for (int rt = 0; rt < 2; ++rt) a[rt] = *(const uint4*)&f_s[(rt*16 + n)*132 + kb*16 + q*4];
    #pragma unroll
    for (int ct = 0; ct < 4; ++ct) bb[ct] = *(const uint4*)(wr1T + (size_t)colg[ct]*128 + kb*16 + q*4);
    #pragma unroll
    for (int rt = 0; rt < 2; ++rt)
      #pragma unroll
      for (int ct = 0; ct < 4; ++ct)
        acc[rt][ct] = __builtin_amdgcn_mfma_f32_16x16x32_bf16(as_s8(a[rt]), as_s8(bb[ct]), acc[rt][ct], 0, 0, 0);
  }
  __syncthreads();   // all f_s reads complete before h16 overlay writes

  {
    float brv[4];
    #pragma unroll
    for (int ct = 0; ct < 4; ++ct) brv[ct] = br1[colg[ct]];
    #pragma unroll
    for (int rt = 0; rt < 2; ++rt)
      #pragma unroll
      for (int ct = 0; ct < 4; ++ct)
        #pragma unroll
        for (int r = 0; r < 4; ++r) {
          int pr = rt*16 + q*4 + r;
          h16[pr*264 + colg[ct]] = bf16_1(fmaxf(acc[rt][ct][r] + brv[ct], 0.f));
        }
  }
  __syncthreads();

  const unsigned* h32 = (const unsigned*)h16;
  #pragma unroll
  for (int rep = 0; rep < 2; ++rep) {
    int oi = rep*256 + t;
    if (oi < 320) {
      int row = oi / 10, o = oi - row*10;
      float a = br2[o];
      #pragma unroll 4
      for (int c2 = 0; c2 < 128; ++c2) {
        unsigned u = h32[row*132 + c2];
        a += bf_lo(u)*w2_s[(2*c2)*10 + o] + bf_hi(u)*w2_s[(2*c2+1)*10 + o];
      }
      int iu = iu_s[row], ju = ju_s[row];
      if (ju < vn) {
        int idx = iu*vn - (iu*(iu+1))/2 + (ju - iu - 1);
        out[(((size_t)b*5 + (o>>1))*PP + idx)*2 + (o&1)] = a;
      }
    }
  }
}

extern "C" void kernel_launch(void* const* d_in, const int* in_sizes, int n_in,
                              void* d_out, int out_size, void* d_ws, size_t ws_size,
                              hipStream_t stream) {
  const int*   edge_ids      = (const int*)d_in[0];
  const float* node_features = (const float*)d_in[1];
  const int*   event_nums    = (const int*)d_in[3];
  const float* emb  = (const float*)d_in[4];
  const float* Wl_e = (const float*)d_in[5];
  const float* Wl_w = (const float*)d_in[6];
  const float* Wl_v = (const float*)d_in[7];
  const float* bl1  = (const float*)d_in[8];
  const float* wl2  = (const float*)d_in[9];
  const float* bl2  = (const float*)d_in[10];
  const float* Wm_w = (const float*)d_in[11];
  const float* Wm_v = (const float*)d_in[12];
  const float* Wm_e = (const float*)d_in[13];
  const float* bm   = (const float*)d_in[14];
  const float* Wu_e = (const float*)d_in[15];
  const float* Wu_m = (const float*)d_in[16];
  const float* bu   = (const float*)d_in[17];
  const float* W_ih = (const float*)d_in[18];
  const float* W_hh = (const float*)d_in[19];
  const float* b_ih = (const float*)d_in[20];
  const float* b_hh = (const float*)d_in[21];
  const float* Wr1  = (const float*)d_in[22];
  const float* br1  = (const float*)d_in[23];
  const float* Wr2  = (const float*)d_in[24];
  const float* br2  = (const float*)d_in[25];

  // workspace carve: e_g 134.2 MB + 6 small (12.6 MB) + packed weights (0.26 MB) + embT
  const size_t SZ_E = (size_t)134217728;       // B*N*N*64 u32
  const size_t SZ_S = (size_t)2097152;         // B*N*128 f32
  const size_t SZ_W = (size_t)131072;          // 32768 u32
  const size_t SZ_EM = (size_t)4096;
  const size_t need = SZ_E + 6*SZ_S + 2*SZ_W + SZ_EM;

  hipMemsetAsync(d_out, 0, (size_t)out_size * sizeof(float), stream);
  if (ws_size < need) return;   // clean failure instead of OOB fault

  char* w = (char*)d_ws;
  unsigned* eg   = (unsigned*)w; w += SZ_E;
  float* h_ws = (float*)w; w += SZ_S;
  float* a_l  = (float*)w; w += SZ_S;
  float* b_l  = (float*)w; w += SZ_S;
  float* a_m  = (float*)w; w += SZ_S;
  float* b_m  = (float*)w; w += SZ_S;
  float* ms   = (float*)w; w += SZ_S;
  unsigned* wT   = (unsigned*)w; w += SZ_W;
  unsigned* wr1T = (unsigned*)w; w += SZ_W;
  unsigned* embT = (unsigned*)w; w += SZ_EM;

  hipLaunchKernelGGL(conv_w_kernel, dim3(256), dim3(256), 0, stream,
      Wl_e, Wm_e, Wu_e, Wu_m, Wr1, emb, wT, wr1T, embT);

  hipLaunchKernelGGL(gru_proj_kernel, dim3(1024), dim3(256), 0, stream,
      0, ms, node_features, h_ws, W_ih, W_hh, b_ih, b_hh,
      Wl_w, Wl_v, Wm_w, Wm_v, event_nums, a_l, b_l, a_m, b_m);

  for (int r = 0; r < 3; ++r) {
    hipLaunchKernelGGL(edge_round_mfma, dim3(4096), dim3(256), 0, stream,
        eg, wT, embT, edge_ids, (r == 0) ? 1 : 0, a_l, b_l, a_m, b_m,
        bl1, wl2, bl2, bm, bu, event_nums, ms);
    if (r < 2) {
      const float* hin = (r == 0) ? node_features : h_ws;
      hipLaunchKernelGGL(gru_proj_kernel, dim3(1024), dim3(256), 0, stream,
          1, ms, hin, h_ws, W_ih, W_hh, b_ih, b_hh,
          Wl_w, Wl_v, Wm_w, Wm_v, event_nums, a_l, b_l, a_m, b_m);
    }
  }

  hipLaunchKernelGGL(readout_mfma, dim3(8128), dim3(256), 0, stream,
      eg, wr1T, br1, Wr2, br2, event_nums, (float*)d_out);
}

// Round 8
// 820.276 us; speedup vs baseline: 1.4074x; 1.0402x over previous
//
#include <hip/hip_runtime.h>
#include <cstddef>

// Problem constants
#define BB 32
#define NN 128
#define PP 8128

typedef __attribute__((ext_vector_type(8))) short short8;
typedef __attribute__((ext_vector_type(4))) float floatx4;

union U4S8 { uint4 u; short8 s; };
__device__ __forceinline__ short8 as_s8(uint4 v){ U4S8 x; x.u = v; return x.s; }

// ---------- bf16 helpers ----------
__device__ __forceinline__ float bf_lo(unsigned u){ union{unsigned v;float f;}x; x.v=u<<16; return x.f; }
__device__ __forceinline__ float bf_hi(unsigned u){ union{unsigned v;float f;}x; x.v=u&0xffff0000u; return x.f; }
__device__ __forceinline__ unsigned pack_bf16(float a, float b){
  union{float f;unsigned u;}xa,xb; xa.f=a; xb.f=b;
  unsigned ua=xa.u, ub=xb.u;
  ua = (ua + 0x7fffu + ((ua>>16)&1u)) >> 16;
  ub = (ub + 0x7fffu + ((ub>>16)&1u)) >> 16;
  return (ua & 0xffffu) | (ub << 16);
}
__device__ __forceinline__ unsigned short bf16_1(float a){
  union{float f;unsigned u;}x; x.f=a;
  return (unsigned short)((x.u + 0x7fffu + ((x.u>>16)&1u)) >> 16);
}
__device__ __forceinline__ float sigf(float x){ return 1.f/(1.f + __expf(-x)); }

// ---------- weight conversion + emb table ----------
__global__ __launch_bounds__(256,4) void conv_w_kernel(
  const float* __restrict__ Wl_e, const float* __restrict__ Wm_e,
  const float* __restrict__ Wu_e, const float* __restrict__ Wu_m,
  const float* __restrict__ Wr1, const float* __restrict__ Wr2,
  const float* __restrict__ emb,
  unsigned* __restrict__ wT, unsigned* __restrict__ wr1T,
  unsigned* __restrict__ wr2T, unsigned* __restrict__ embT)
{
  int tid = blockIdx.x*256 + threadIdx.x;   // 65536 total
  if (tid < 256) {
    int id = tid >> 6, k2 = tid & 63;
    embT[tid] = pack_bf16(emb[id*128 + 2*k2], emb[id*128 + 2*k2 + 1]);
  }
  if (tid < 2048) {   // Wr2 [256][10] -> B-frag layout [16 cols][128 k2], zero-padded
    int c = tid >> 7, k2 = tid & 127;
    unsigned v = 0;
    if (c < 10) v = pack_bf16(Wr2[(2*k2)*10 + c], Wr2[(2*k2+1)*10 + c]);
    wr2T[c*128 + k2] = v;
  }
  if (tid < 32768) {
    int mat = tid >> 13, r = tid & 8191;
    int k2 = r >> 7, c = r & 127;
    const float* W = (mat==0) ? Wl_e : (mat==1) ? Wm_e : (mat==2) ? Wu_e : Wu_m;
    wT[mat*8192 + c*64 + k2] = pack_bf16(W[(2*k2)*128 + c], W[(2*k2+1)*128 + c]);
  } else {
    int r = tid - 32768;
    int k2 = r >> 8, c = r & 255;
    wr1T[(size_t)c*128 + k2] = pack_bf16(Wr1[(2*k2)*256 + c], Wr1[(2*k2+1)*256 + c]);
  }
}

// ---------- fused GRU + node projections ----------
__global__ __launch_bounds__(256,4) void gru_proj_kernel(
  int do_gru,
  const float* __restrict__ ms, const float* __restrict__ h_in, float* __restrict__ h_out,
  const float* __restrict__ W_ih, const float* __restrict__ W_hh,
  const float* __restrict__ b_ih, const float* __restrict__ b_hh,
  const float* __restrict__ Wl_w, const float* __restrict__ Wl_v,
  const float* __restrict__ Wm_w, const float* __restrict__ Wm_v,
  const int* __restrict__ event_nums,
  float* __restrict__ a_l, float* __restrict__ b_l,
  float* __restrict__ a_m, float* __restrict__ b_m)
{
  __shared__ float h_s[4][128];
  __shared__ float ms_s[4][128];
  const int t = threadIdx.x, blk = blockIdx.x;
  const int b = blk >> 5, n0 = (blk & 31) * 4;
  const int vn = event_nums[b];
  const int g = t >> 6, l = t & 63;
  const int row = b*128 + n0 + g;

  h_s[g][l]    = h_in[(size_t)row*128 + l];
  h_s[g][l+64] = h_in[(size_t)row*128 + l + 64];
  if (do_gru) {
    ms_s[g][l]    = ms[(size_t)row*128 + l];
    ms_s[g][l+64] = ms[(size_t)row*128 + l + 64];
  }
  __syncthreads();

  if (do_gru) {
    float acc[12] = {};
    #pragma unroll 4
    for (int k = 0; k < 128; ++k) {
      float mv = ms_s[g][k], hv = h_s[g][k];
      #pragma unroll
      for (int u = 0; u < 6; ++u) {
        acc[u]   += mv * W_ih[(size_t)k*384 + l + 64*u];
        acc[6+u] += hv * W_hh[(size_t)k*384 + l + 64*u];
      }
    }
    const bool valid = (n0 + g) < vn;
    float hnew[2];
    #pragma unroll
    for (int u = 0; u < 2; ++u) {
      int c = l + 64*u;
      float ir = acc[u]     + b_ih[c];
      float iz = acc[u+2]   + b_ih[128+c];
      float in_= acc[u+4]   + b_ih[256+c];
      float hr = acc[6+u]   + b_hh[c];
      float hz = acc[8+u]   + b_hh[128+c];
      float hn = acc[10+u]  + b_hh[256+c];
      float r  = sigf(ir + hr);
      float zg = sigf(iz + hz);
      float nn = tanhf(in_ + r*hn);
      float hold = h_s[g][c];
      hnew[u] = valid ? (1.f - zg)*nn + zg*hold : hold;
    }
    __syncthreads();
    #pragma unroll
    for (int u = 0; u < 2; ++u) {
      int c = l + 64*u;
      h_s[g][c] = hnew[u];
      h_out[(size_t)row*128 + c] = hnew[u];
    }
    __syncthreads();
  }

  {
    const float* Wp[4] = {Wl_w, Wl_v, Wm_w, Wm_v};
    float* Op[4] = {a_l, b_l, a_m, b_m};
    float acc2[8] = {};
    #pragma unroll 4
    for (int k = 0; k < 128; ++k) {
      float hv = h_s[g][k];
      #pragma unroll
      for (int u = 0; u < 8; ++u)
        acc2[u] += hv * Wp[u>>1][(size_t)k*128 + l + 64*(u&1)];
    }
    #pragma unroll
    for (int u = 0; u < 8; ++u)
      Op[u>>1][(size_t)row*128 + l + 64*(u&1)] = acc2[u];
  }
}

// ---------- MFMA edge-round kernel: 3 single-accumulator passes ----------
// grid = B*N, block 256 = 4 waves in 2x2 (rowhalf x colhalf).
// A-frags read directly from global (L2-resident across passes); only m_a in LDS.
// Per-pass regs ~64 AGPR + ~60 VGPR -> 3 waves/SIMD under (256,3), no spill.
__global__ __launch_bounds__(256,3) void edge_round_mfma(
  unsigned* __restrict__ eg,           // [B][N(j)][N(i)][64] bf16-pairs
  const unsigned* __restrict__ wT,     // [Wl_e|Wm_e|Wu_e|Wu_m] each [c][64] bf16-pairs
  const unsigned* __restrict__ embT,   // [4][64] bf16-pairs
  const int* __restrict__ ids,         // [B][N][N]
  int first,
  const float* __restrict__ a_l, const float* __restrict__ b_l,
  const float* __restrict__ a_m, const float* __restrict__ b_m,
  const float* __restrict__ bl1, const float* __restrict__ wl2,
  const float* __restrict__ bl2, const float* __restrict__ bm,
  const float* __restrict__ bu,
  const int* __restrict__ event_nums,
  float* __restrict__ ms)
{
  __shared__ unsigned m_a[128*68];   // m (later u) as bf16, padded rows (68 words)
  __shared__ float adj[128], svec[128], msum[128];
  __shared__ float bL_s[128], bM_s[128], bu_s[128], wl2_s[128];
  __shared__ unsigned emb_s[4*68];
  __shared__ int id_s[128];
  unsigned short* m16 = (unsigned short*)m_a;

  const int t = threadIdx.x;
  const int b = blockIdx.x >> 7, j = blockIdx.x & 127;
  const int vn = event_nums[b];
  unsigned* eblk = eg + (size_t)(b*128 + j) * 8192;   // 128 rows x 64 k2

  if (j >= vn) {
    if (t < 128) ms[(size_t)(b*128 + j)*128 + t] = 0.f;
    return;
  }

  if (t < 128) {
    bL_s[t] = b_l[(size_t)(b*128 + j)*128 + t] + bl1[t];
    bM_s[t] = b_m[(size_t)(b*128 + j)*128 + t] + bm[t];
    bu_s[t] = bu[t];
    wl2_s[t] = wl2[t];
    adj[t] = 0.f; msum[t] = 0.f;
    if (first) id_s[t] = ids[((size_t)(b*128 + t))*128 + j];
  }
  if (first && t < 256) emb_s[(t >> 6)*68 + (t & 63)] = embT[t];
  __syncthreads();

  const int lane = t & 63, wv = t >> 6;
  const int q = lane >> 4, n = lane & 15;
  const int rh = wv >> 1, ch = wv & 1;
  const bool fst = (first != 0);

  int nvt = (vn - rh*64 + 15) >> 4;
  nvt = nvt < 0 ? 0 : (nvt > 4 ? 4 : nvt);

  const unsigned* wz  = wT;
  const unsigned* wm  = wT + 8192;
  const unsigned* wue = wT + 16384;
  const unsigned* wum = wT + 24576;

  int colg[4];
  #pragma unroll
  for (int ct = 0; ct < 4; ++ct) colg[ct] = ch*64 + ct*16 + n;

  int arowi[4];
  #pragma unroll
  for (int rt = 0; rt < 4; ++rt) arowi[rt] = rh*64 + rt*16 + n;

  // ---------- PASS Z ----------
  {
    floatx4 acc[4][4];
    #pragma unroll
    for (int rt = 0; rt < 4; ++rt)
      #pragma unroll
      for (int ct = 0; ct < 4; ++ct) acc[rt][ct] = (floatx4){0.f,0.f,0.f,0.f};
    #pragma unroll
    for (int kb = 0; kb < 4; ++kb) {
      uint4 bb[4];
      #pragma unroll
      for (int ct = 0; ct < 4; ++ct) bb[ct] = *(const uint4*)(wz + colg[ct]*64 + kb*16 + q*4);
      #pragma unroll
      for (int rt = 0; rt < 4; ++rt) {
        if (rt < nvt) {
          uint4 a;
          if (fst) a = *(const uint4*)&emb_s[id_s[arowi[rt]]*68 + kb*16 + q*4];
          else     a = *(const uint4*)(eblk + (size_t)arowi[rt]*64 + kb*16 + q*4);
          #pragma unroll
          for (int ct = 0; ct < 4; ++ct)
            acc[rt][ct] = __builtin_amdgcn_mfma_f32_16x16x32_bf16(as_s8(a), as_s8(bb[ct]), acc[rt][ct], 0, 0, 0);
        }
      }
    }
    // z epilogue: adj[row] += sum_col relu(z + a_l + bL) * wl2
    float wl2v[4], bLv[4];
    #pragma unroll
    for (int ct = 0; ct < 4; ++ct) { wl2v[ct] = wl2_s[colg[ct]]; bLv[ct] = bL_s[colg[ct]]; }
    #pragma unroll
    for (int rt = 0; rt < 4; ++rt) {
      if (rt < nvt) {
        float szr[4] = {0.f,0.f,0.f,0.f};
        #pragma unroll
        for (int ct = 0; ct < 4; ++ct) {
          #pragma unroll
          for (int r = 0; r < 4; ++r) {
            int row = rh*64 + rt*16 + q*4 + r;
            float al = a_l[(size_t)(b*128 + row)*128 + colg[ct]];
            float zv = fmaxf(acc[rt][ct][r] + al + bLv[ct], 0.f);
            szr[r] += zv * wl2v[ct];
          }
        }
        #pragma unroll
        for (int r = 0; r < 4; ++r) {
          szr[r] += __shfl_xor(szr[r], 1);
          szr[r] += __shfl_xor(szr[r], 2);
          szr[r] += __shfl_xor(szr[r], 4);
          szr[r] += __shfl_xor(szr[r], 8);
        }
        if (n == 0) {
          #pragma unroll
          for (int r = 0; r < 4; ++r)
            atomicAdd(&adj[rh*64 + rt*16 + q*4 + r], szr[r]);
        }
      }
    }
  }
  __syncthreads();
  if (t < 128) svec[t] = sigf(adj[t] + bl2[0]);
  __syncthreads();

  // ---------- PASS M ----------
  {
    floatx4 acc[4][4];
    #pragma unroll
    for (int rt = 0; rt < 4; ++rt)
      #pragma unroll
      for (int ct = 0; ct < 4; ++ct) acc[rt][ct] = (floatx4){0.f,0.f,0.f,0.f};
    #pragma unroll
    for (int kb = 0; kb < 4; ++kb) {
      uint4 bb[4];
      #pragma unroll
      for (int ct = 0; ct < 4; ++ct) bb[ct] = *(const uint4*)(wm + colg[ct]*64 + kb*16 + q*4);
      #pragma unroll
      for (int rt = 0; rt < 4; ++rt) {
        if (rt < nvt) {
          uint4 a;
          if (fst) a = *(const uint4*)&emb_s[id_s[arowi[rt]]*68 + kb*16 + q*4];
          else     a = *(const uint4*)(eblk + (size_t)arowi[rt]*64 + kb*16 + q*4);
          #pragma unroll
          for (int ct = 0; ct < 4; ++ct)
            acc[rt][ct] = __builtin_amdgcn_mfma_f32_16x16x32_bf16(as_s8(a), as_s8(bb[ct]), acc[rt][ct], 0, 0, 0);
        }
      }
    }
    // m epilogue
    float bMv[4];
    #pragma unroll
    for (int ct = 0; ct < 4; ++ct) bMv[ct] = bM_s[colg[ct]];
    float colsum[4] = {0.f,0.f,0.f,0.f};
    #pragma unroll
    for (int rt = 0; rt < 4; ++rt) {
      if (rt < nvt) {
        #pragma unroll
        for (int ct = 0; ct < 4; ++ct) {
          #pragma unroll
          for (int r = 0; r < 4; ++r) {
            int row = rh*64 + rt*16 + q*4 + r;
            float am = a_m[(size_t)(b*128 + row)*128 + colg[ct]];
            float mv = fmaxf(acc[rt][ct][r] + am + bMv[ct], 0.f);
            float sc = (row < vn) ? svec[row] : 0.f;
            mv *= sc;
            m16[row*136 + colg[ct]] = bf16_1(mv);
            colsum[ct] += mv;
          }
        }
      }
    }
    #pragma unroll
    for (int ct = 0; ct < 4; ++ct) {
      float v = colsum[ct];
      v += __shfl_xor(v, 16);
      v += __shfl_xor(v, 32);
      if (lane < 16) atomicAdd(&msum[colg[ct]], v);
    }
  }
  __syncthreads();
  if (t < 128) ms[(size_t)(b*128 + j)*128 + t] = msum[t];

  // ---------- PASS U: U = E@Wu_e + M@Wu_m ----------
  floatx4 accu[4][4];
  #pragma unroll
  for (int rt = 0; rt < 4; ++rt)
    #pragma unroll
    for (int ct = 0; ct < 4; ++ct) accu[rt][ct] = (floatx4){0.f,0.f,0.f,0.f};
  #pragma unroll
  for (int kb = 0; kb < 4; ++kb) {
    uint4 bb[4];
    #pragma unroll
    for (int ct = 0; ct < 4; ++ct) bb[ct] = *(const uint4*)(wue + colg[ct]*64 + kb*16 + q*4);
    #pragma unroll
    for (int rt = 0; rt < 4; ++rt) {
      if (rt < nvt) {
        uint4 a;
        if (fst) a = *(const uint4*)&emb_s[id_s[arowi[rt]]*68 + kb*16 + q*4];
        else     a = *(const uint4*)(eblk + (size_t)arowi[rt]*64 + kb*16 + q*4);
        #pragma unroll
        for (int ct = 0; ct < 4; ++ct)
          accu[rt][ct] = __builtin_amdgcn_mfma_f32_16x16x32_bf16(as_s8(a), as_s8(bb[ct]), accu[rt][ct], 0, 0, 0);
      }
    }
  }
  #pragma unroll
  for (int kb = 0; kb < 4; ++kb) {
    uint4 bb[4];
    #pragma unroll
    for (int ct = 0; ct < 4; ++ct) bb[ct] = *(const uint4*)(wum + colg[ct]*64 + kb*16 + q*4);
    #pragma unroll
    for (int rt = 0; rt < 4; ++rt) {
      if (rt < nvt) {
        uint4 a = *(const uint4*)&m_a[arowi[rt]*68 + kb*16 + q*4];
        #pragma unroll
        for (int ct = 0; ct < 4; ++ct)
          accu[rt][ct] = __builtin_amdgcn_mfma_f32_16x16x32_bf16(as_s8(a), as_s8(bb[ct]), accu[rt][ct], 0, 0, 0);
      }
    }
  }
  __syncthreads();   // all m_a reads done before overwrite

  {
    float buv[4];
    #pragma unroll
    for (int ct = 0; ct < 4; ++ct) buv[ct] = bu_s[colg[ct]];
    #pragma unroll
    for (int rt = 0; rt < 4; ++rt) {
      if (rt < nvt) {
        #pragma unroll
        for (int ct = 0; ct < 4; ++ct)
          #pragma unroll
          for (int r = 0; r < 4; ++r) {
            int row = rh*64 + rt*16 + q*4 + r;
            m16[row*136 + colg[ct]] = bf16_1(fmaxf(accu[rt][ct][r] + buv[ct], 0.f));
          }
      }
    }
  }
  __syncthreads();
  #pragma unroll
  for (int it = 0; it < 32; ++it) {
    int f = it*256 + t;
    int row = f >> 6, c2 = f & 63;
    if (row < vn) eblk[row*64 + c2] = m_a[row*68 + c2];
  }
}

// ---------- MFMA readout, both GEMMs on matrix cores ----------
// grid = B*127 (64 pairs/block), block 256 = 4 waves over 4 column-quarters of 256.
__global__ __launch_bounds__(256,4) void readout_mfma(
  const unsigned* __restrict__ eg,
  const unsigned* __restrict__ wr1T,   // [256 cols][128 k2] bf16-pairs
  const unsigned* __restrict__ wr2T,   // [16 cols][128 k2] bf16-pairs (cols 10..15 zero)
  const float* __restrict__ br1, const float* __restrict__ br2,
  const int* __restrict__ event_nums, float* __restrict__ out)
{
  __shared__ unsigned f_s[64*132];     // feat bf16 pairs, padded rows; reused as h16
  __shared__ int iu_s[64], ju_s[64];
  unsigned short* h16 = (unsigned short*)f_s;   // overlay: 64 rows x 264 halves

  const int t = threadIdx.x;
  const int b = blockIdx.x / 127, pb = blockIdx.x % 127;
  const int vn = event_nums[b];

  if (t < 64) {
    int p = pb*64 + t;
    float disc = (float)((2*NN-1)*(2*NN-1) - 8*p);
    int iu = (int)(((float)(2*NN-1) - sqrtf(disc)) * 0.5f);
    if (iu < 0) iu = 0; if (iu > NN-2) iu = NN-2;
    while (iu < NN-2 && ((iu+1)*(2*NN-2-iu))/2 <= p) ++iu;
    while (iu > 0 && (iu*(2*NN-1-iu))/2 > p) --iu;
    int ju = p - (iu*(2*NN-1-iu))/2 + iu + 1;
    iu_s[t] = iu; ju_s[t] = ju;
  }
  __syncthreads();

  // stage feat: 64 rows (pairs) x 128 words; w<64 = e[b,iu,ju,:], w>=64 = e[b,ju,iu,:]
  #pragma unroll
  for (int it = 0; it < 32; ++it) {
    int f = it*256 + t;
    int pr = f >> 7, w = f & 127;
    int side = w >> 6, k2l = w & 63;
    int iu = iu_s[pr], ju = ju_s[pr];
    size_t base = side ? (((size_t)(b*128 + iu))*128 + ju)*64
                       : (((size_t)(b*128 + ju))*128 + iu)*64;
    f_s[pr*132 + w] = eg[base + k2l];
  }
  __syncthreads();

  const int lane = t & 63, wv = t >> 6;
  const int q = lane >> 4, n = lane & 15;
  int colg[4];
  #pragma unroll
  for (int ct = 0; ct < 4; ++ct) colg[ct] = wv*64 + ct*16 + n;

  // GEMM1: hidden = relu(feat @ Wr1 + br1); 64 rows x 256 cols, K=512
  floatx4 acc[4][4];
  #pragma unroll
  for (int rt = 0; rt < 4; ++rt)
    #pragma unroll
    for (int ct = 0; ct < 4; ++ct) acc[rt][ct] = (floatx4){0.f,0.f,0.f,0.f};

  #pragma unroll
  for (int kb = 0; kb < 8; ++kb) {
    uint4 bb[4];
    #pragma unroll
    for (int ct = 0; ct < 4; ++ct) bb[ct] = *(const uint4*)(wr1T + (size_t)colg[ct]*128 + kb*16 + q*4);
    #pragma unroll
    for (int rt = 0; rt < 4; ++rt) {
      uint4 a = *(const uint4*)&f_s[(rt*16 + n)*132 + kb*16 + q*4];
      #pragma unroll
      for (int ct = 0; ct < 4; ++ct)
        acc[rt][ct] = __builtin_amdgcn_mfma_f32_16x16x32_bf16(as_s8(a), as_s8(bb[ct]), acc[rt][ct], 0, 0, 0);
    }
  }
  __syncthreads();   // all f_s reads complete before h16 overlay writes

  {
    float brv[4];
    #pragma unroll
    for (int ct = 0; ct < 4; ++ct) brv[ct] = br1[colg[ct]];
    #pragma unroll
    for (int rt = 0; rt < 4; ++rt)
      #pragma unroll
      for (int ct = 0; ct < 4; ++ct)
        #pragma unroll
        for (int r = 0; r < 4; ++r) {
          int pr = rt*16 + q*4 + r;
          h16[pr*264 + colg[ct]] = bf16_1(fmaxf(acc[rt][ct][r] + brv[ct], 0.f));
        }
  }
  __syncthreads();

  // GEMM2: out = hidden @ Wr2 (cols padded to 16); wave wv owns rows wv*16..+15
  floatx4 acc2 = (floatx4){0.f,0.f,0.f,0.f};
  #pragma unroll
  for (int kb = 0; kb < 8; ++kb) {
    uint4 bb = *(const uint4*)(wr2T + n*128 + kb*16 + q*4);
    uint4 a  = *(const uint4*)&f_s[(wv*16 + n)*132 + kb*16 + q*4];
    acc2 = __builtin_amdgcn_mfma_f32_16x16x32_bf16(as_s8(a), as_s8(bb), acc2, 0, 0, 0);
  }

  if (n < 10) {
    float bias = br2[n];
    #pragma unroll
    for (int r = 0; r < 4; ++r) {
      int pr = wv*16 + q*4 + r;
      int iu = iu_s[pr], ju = ju_s[pr];
      if (ju < vn) {
        int idx = iu*vn - (iu*(iu+1))/2 + (ju - iu - 1);
        out[(((size_t)b*5 + (n>>1))*PP + idx)*2 + (n&1)] = acc2[r] + bias;
      }
    }
  }
}

extern "C" void kernel_launch(void* const* d_in, const int* in_sizes, int n_in,
                              void* d_out, int out_size, void* d_ws, size_t ws_size,
                              hipStream_t stream) {
  const int*   edge_ids      = (const int*)d_in[0];
  const float* node_features = (const float*)d_in[1];
  const int*   event_nums    = (const int*)d_in[3];
  const float* emb  = (const float*)d_in[4];
  const float* Wl_e = (const float*)d_in[5];
  const float* Wl_w = (const float*)d_in[6];
  const float* Wl_v = (const float*)d_in[7];
  const float* bl1  = (const float*)d_in[8];
  const float* wl2  = (const float*)d_in[9];
  const float* bl2  = (const float*)d_in[10];
  const float* Wm_w = (const float*)d_in[11];
  const float* Wm_v = (const float*)d_in[12];
  const float* Wm_e = (const float*)d_in[13];
  const float* bm   = (const float*)d_in[14];
  const float* Wu_e = (const float*)d_in[15];
  const float* Wu_m = (const float*)d_in[16];
  const float* bu   = (const float*)d_in[17];
  const float* W_ih = (const float*)d_in[18];
  const float* W_hh = (const float*)d_in[19];
  const float* b_ih = (const float*)d_in[20];
  const float* b_hh = (const float*)d_in[21];
  const float* Wr1  = (const float*)d_in[22];
  const float* br1  = (const float*)d_in[23];
  const float* Wr2  = (const float*)d_in[24];
  const float* br2  = (const float*)d_in[25];

  const size_t SZ_E = (size_t)134217728;       // B*N*N*64 u32
  const size_t SZ_S = (size_t)2097152;         // B*N*128 f32
  const size_t SZ_W = (size_t)131072;          // 32768 u32
  const size_t SZ_W2 = (size_t)8192;           // 2048 u32
  const size_t SZ_EM = (size_t)4096;
  const size_t need = SZ_E + 6*SZ_S + 2*SZ_W + SZ_W2 + SZ_EM;

  hipMemsetAsync(d_out, 0, (size_t)out_size * sizeof(float), stream);
  if (ws_size < need) return;   // clean failure instead of OOB fault

  char* w = (char*)d_ws;
  unsigned* eg   = (unsigned*)w; w += SZ_E;
  float* h_ws = (float*)w; w += SZ_S;
  float* a_l  = (float*)w; w += SZ_S;
  float* b_l  = (float*)w; w += SZ_S;
  float* a_m  = (float*)w; w += SZ_S;
  float* b_m  = (float*)w; w += SZ_S;
  float* ms   = (float*)w; w += SZ_S;
  unsigned* wT   = (unsigned*)w; w += SZ_W;
  unsigned* wr1T = (unsigned*)w; w += SZ_W;
  unsigned* wr2T = (unsigned*)w; w += SZ_W2;
  unsigned* embT = (unsigned*)w; w += SZ_EM;

  hipLaunchKernelGGL(conv_w_kernel, dim3(256), dim3(256), 0, stream,
      Wl_e, Wm_e, Wu_e, Wu_m, Wr1, Wr2, emb, wT, wr1T, wr2T, embT);

  hipLaunchKernelGGL(gru_proj_kernel, dim3(1024), dim3(256), 0, stream,
      0, ms, node_features, h_ws, W_ih, W_hh, b_ih, b_hh,
      Wl_w, Wl_v, Wm_w, Wm_v, event_nums, a_l, b_l, a_m, b_m);

  for (int r = 0; r < 3; ++r) {
    hipLaunchKernelGGL(edge_round_mfma, dim3(4096), dim3(256), 0, stream,
        eg, wT, embT, edge_ids, (r == 0) ? 1 : 0, a_l, b_l, a_m, b_m,
        bl1, wl2, bl2, bm, bu, event_nums, ms);
    if (r < 2) {
      const float* hin = (r == 0) ? node_features : h_ws;
      hipLaunchKernelGGL(gru_proj_kernel, dim3(1024), dim3(256), 0, stream,
          1, ms, hin, h_ws, W_ih, W_hh, b_ih, b_hh,
          Wl_w, Wl_v, Wm_w, Wm_v, event_nums, a_l, b_l, a_m, b_m);
    }
  }

  hipLaunchKernelGGL(readout_mfma, dim3(BB*127), dim3(256), 0, stream,
      eg, wr1T, wr2T, br1, br2, event_nums, (float*)d_out);
}